// Round 2
// 8000.210 us; speedup vs baseline: 1.0224x; 1.0224x over previous
//
#include <hip/hip_runtime.h>
#include <hip/hip_bf16.h>
#include <cstddef>

#define NN 20000
#define EE 400000
#define TT 1500000
#define BB 128
#define HH 128
#define INTD 64
#define OUT_EMB 256
#define SBF_DIM 42
#define NRAD 6

#define SA_C 136   // Cs row stride (ushorts): 272B, 16B-aligned, 2-way bank (free)
#define SA_B 72    // Bs row stride (ushorts): 144B, 16B-aligned, 2-way bank (free)

typedef __attribute__((ext_vector_type(8))) short bf16x8;
typedef __attribute__((ext_vector_type(4))) float f32x4;

__device__ __forceinline__ float silu_f(float v) {
    return v / (1.0f + __expf(-v));
}
__device__ __forceinline__ unsigned short f2b(float f) {
    __hip_bfloat16 h = __float2bfloat16(f);
    unsigned short u; __builtin_memcpy(&u, &h, 2); return u;
}
__device__ __forceinline__ float b2f(unsigned short u) {
    __hip_bfloat16 h; __builtin_memcpy(&h, &u, 2); return __bfloat162float(h);
}

__device__ __forceinline__ void zero_acc(f32x4 a[4][4]) {
#pragma unroll
    for (int mi = 0; mi < 4; ++mi)
#pragma unroll
        for (int ni = 0; ni < 4; ++ni) a[mi][ni] = (f32x4){0.f, 0.f, 0.f, 0.f};
}

// --- async weight staging: global->reg (issue early), reg->LDS (after barrier) ---
// ITEMS = rows*8/256 (4 for 128-row W, 2 for 64-row W)
template <int ITEMS>
__device__ __forceinline__ void loadW(uint4 (&rg)[ITEMS], const unsigned short* W,
                                      int rowstride, int kofs, int tid) {
#pragma unroll
    for (int j = 0; j < ITEMS; ++j) {
        int i = tid + j * 256;
        int n = i >> 3, seg = i & 7;
        rg[j] = *(const uint4*)(W + (size_t)n * rowstride + kofs + seg * 8);
    }
}
template <int ITEMS>
__device__ __forceinline__ void storeW(const uint4 (&rg)[ITEMS], unsigned short* Bs, int tid) {
#pragma unroll
    for (int j = 0; j < ITEMS; ++j) {
        int i = tid + j * 256;
        int n = i >> 3, seg = i & 7;
        *(uint4*)&Bs[n * SA_B + seg * 8] = rg[j];
    }
}

// packed epilogue store: 4 consecutive features of one edge row -> ds_write_b64
__device__ __forceinline__ void st4(unsigned short* Cs, int m, int f0, const float* v) {
    ushort4 u = make_ushort4(f2b(v[0]), f2b(v[1]), f2b(v[2]), f2b(v[3]));
    *(ushort4*)&Cs[m * SA_C + f0] = u;
}

// Operand-swapped 64x64 wave tile: A = W^T rows (features, from Bs),
// B = X rows (edges, from Cs). Output: row = feature (quad*4+r), col = edge (lm).
__device__ __forceinline__ void mfma_chunk(const unsigned short* Cs, int kofs,
                                           const unsigned short* Bs, int lm, int quad,
                                           int fw0, int ew0, f32x4 acc[4][4]) {
#pragma unroll
    for (int kc = 0; kc < 2; ++kc) {
        bf16x8 wf[4], xf[4];
#pragma unroll
        for (int mi = 0; mi < 4; ++mi)
            wf[mi] = *(const bf16x8*)&Bs[(fw0 + mi * 16 + lm) * SA_B + kc * 32 + quad * 8];
#pragma unroll
        for (int ni = 0; ni < 4; ++ni)
            xf[ni] = *(const bf16x8*)&Cs[(ew0 + ni * 16 + lm) * SA_C + kofs + kc * 32 + quad * 8];
#pragma unroll
        for (int mi = 0; mi < 4; ++mi)
#pragma unroll
            for (int ni = 0; ni < 4; ++ni)
                acc[mi][ni] = __builtin_amdgcn_mfma_f32_16x16x32_bf16(wf[mi], xf[ni], acc[mi][ni], 0, 0, 0);
    }
}

// down GEMM: output [64 dfeat] x [32 edges] per wave (4 feat blocks x 2 edge blocks)
__device__ __forceinline__ void mfma_chunk_d(const unsigned short* Cs, int kofs,
                                             const unsigned short* Bs, int lm, int quad,
                                             int ew0d, f32x4 acc[4][2]) {
#pragma unroll
    for (int kc = 0; kc < 2; ++kc) {
        bf16x8 wf[4], xf[2];
#pragma unroll
        for (int mi = 0; mi < 4; ++mi)
            wf[mi] = *(const bf16x8*)&Bs[(mi * 16 + lm) * SA_B + kc * 32 + quad * 8];
#pragma unroll
        for (int ni = 0; ni < 2; ++ni)
            xf[ni] = *(const bf16x8*)&Cs[(ew0d + ni * 16 + lm) * SA_C + kofs + kc * 32 + quad * 8];
#pragma unroll
        for (int mi = 0; mi < 4; ++mi)
#pragma unroll
            for (int ni = 0; ni < 2; ++ni)
                acc[mi][ni] = __builtin_amdgcn_mfma_f32_16x16x32_bf16(wf[mi], xf[ni], acc[mi][ni], 0, 0, 0);
    }
}

// ---------------------------------------------------------------------------
// MK1: x_ji = silu(e1@Wji+bji) -> buf1 ; x_kj = silu(e1@Wkj+bkj)*r ;
//      bufC = silu(x_kjr @ Wdown)          [one 128-row tile per block]
// ---------------------------------------------------------------------------
__global__ __launch_bounds__(256)
void mk1(const unsigned short* __restrict__ e1b,
         const unsigned short* __restrict__ w_ji, const unsigned short* __restrict__ w_kj,
         const unsigned short* __restrict__ w_down,
         const float* __restrict__ be_ji, const float* __restrict__ be_kj,
         const float* __restrict__ rbf, const float* __restrict__ Crbf_l,
         unsigned short* __restrict__ buf1, unsigned short* __restrict__ bufC) {
    __shared__ unsigned short Cs[128 * SA_C];
    __shared__ unsigned short Bs[128 * SA_B];
    __shared__ float rbfS[128 * 6];
    __shared__ float CrbfS[768];

    const int tid = threadIdx.x;
    const size_t row0 = (size_t)blockIdx.x * 128;
    const int lane = tid & 63, wave = tid >> 6, lm = lane & 15, quad = lane >> 4;
    const int rw0 = (wave >> 1) * 64;   // feature offset (output fragment rows)
    const int cw0 = (wave & 1) * 64;    // edge offset (output fragment cols)
    const int ew0d = wave * 32;         // down-GEMM edge offset

    uint4 wreg[4]; uint4 wregd[2];

    // initial staging: Cs <- e1b tile (full K=128), Bs <- Wji half0, rbf+Crbf tiles
    for (int i = tid; i < 128 * 16; i += 256) {
        int r = i >> 4, seg = i & 15;
        *(uint4*)&Cs[r * SA_C + seg * 8] = *(const uint4*)(e1b + (row0 + r) * 128 + seg * 8);
    }
    loadW<4>(wreg, w_ji, 128, 0, tid); storeW<4>(wreg, Bs, tid);
    for (int i = tid; i < 768; i += 256) { rbfS[i] = rbf[row0 * 6 + i]; CrbfS[i] = Crbf_l[i]; }
    __syncthreads();

    // ---- ji GEMM -> jreg (kept in registers) ----
    f32x4 jreg[4][4], acc[4][4];
    zero_acc(jreg);
    loadW<4>(wreg, w_ji, 128, 64, tid);
    mfma_chunk(Cs, 0, Bs, lm, quad, rw0, cw0, jreg);
    __syncthreads();
    storeW<4>(wreg, Bs, tid);
    __syncthreads();
    loadW<4>(wreg, w_kj, 128, 0, tid);
    mfma_chunk(Cs, 64, Bs, lm, quad, rw0, cw0, jreg);
    __syncthreads();
    storeW<4>(wreg, Bs, tid);
    __syncthreads();

    // ---- kj GEMM ----
    zero_acc(acc);
    loadW<4>(wreg, w_kj, 128, 64, tid);
    mfma_chunk(Cs, 0, Bs, lm, quad, rw0, cw0, acc);
    __syncthreads();
    storeW<4>(wreg, Bs, tid);
    __syncthreads();
    loadW<2>(wregd, w_down, 128, 0, tid);
    mfma_chunk(Cs, 64, Bs, lm, quad, rw0, cw0, acc);
    __syncthreads();
    // epi kj: silu + bias, r-scale; packed writes overwrite Cs
#pragma unroll
    for (int mi = 0; mi < 4; ++mi) {
        const int f0 = rw0 + mi * 16 + quad * 4;
        const float4 bb = *(const float4*)(be_kj + f0);
#pragma unroll
        for (int ni = 0; ni < 4; ++ni) {
            const int m = cw0 + ni * 16 + lm;
            float4 rv = {0.f, 0.f, 0.f, 0.f};
#pragma unroll
            for (int j = 0; j < 6; ++j) {
                float rb = rbfS[m * 6 + j];
                float4 c4 = *(const float4*)&CrbfS[j * 128 + f0];
                rv.x += rb * c4.x; rv.y += rb * c4.y; rv.z += rb * c4.z; rv.w += rb * c4.w;
            }
            float v4[4];
#pragma unroll
            for (int r = 0; r < 4; ++r) {
                float v = silu_f(acc[mi][ni][r] + (&bb.x)[r]);
                v4[r] = b2f(f2b(v)) * (&rv.x)[r];
            }
            st4(Cs, m, f0, v4);
        }
    }
    storeW<2>(wregd, Bs, tid);
    __syncthreads();

    // ---- down GEMM (output 64 dfeat x 128 edges) ----
    f32x4 accd[4][2];
#pragma unroll
    for (int mi = 0; mi < 4; ++mi)
#pragma unroll
        for (int ni = 0; ni < 2; ++ni) accd[mi][ni] = (f32x4){0.f, 0.f, 0.f, 0.f};
    loadW<2>(wregd, w_down, 128, 64, tid);
    mfma_chunk_d(Cs, 0, Bs, lm, quad, ew0d, accd);
    __syncthreads();
    storeW<2>(wregd, Bs, tid);
    __syncthreads();
    mfma_chunk_d(Cs, 64, Bs, lm, quad, ew0d, accd);
    __syncthreads();
    // epi down -> Cs cols 0..63, packed
#pragma unroll
    for (int mi = 0; mi < 4; ++mi) {
        const int f0 = mi * 16 + quad * 4;
#pragma unroll
        for (int ni = 0; ni < 2; ++ni) {
            const int m = ew0d + ni * 16 + lm;
            float v4[4];
#pragma unroll
            for (int r = 0; r < 4; ++r) v4[r] = silu_f(accd[mi][ni][r]);
            st4(Cs, m, f0, v4);
        }
    }
    __syncthreads();
    // coalesced copy Cs(128x64) -> bufC
    for (int i = tid; i < 128 * 8; i += 256) {
        int r = i >> 3, seg = i & 7;
        *(uint4*)(bufC + (row0 + r) * 64 + seg * 8) = *(const uint4*)&Cs[r * SA_C + seg * 8];
    }
    __syncthreads();
    // epi ji -> Cs (packed), then coalesced copy -> buf1
#pragma unroll
    for (int mi = 0; mi < 4; ++mi) {
        const int f0 = rw0 + mi * 16 + quad * 4;
        const float4 bj = *(const float4*)(be_ji + f0);
#pragma unroll
        for (int ni = 0; ni < 4; ++ni) {
            const int m = cw0 + ni * 16 + lm;
            float v4[4];
#pragma unroll
            for (int r = 0; r < 4; ++r) v4[r] = silu_f(jreg[mi][ni][r] + (&bj.x)[r]);
            st4(Cs, m, f0, v4);
        }
    }
    __syncthreads();
    for (int i = tid; i < 128 * 16; i += 256) {
        int r = i >> 4, seg = i & 15;
        *(uint4*)(buf1 + (row0 + r) * 128 + seg * 8) = *(const uint4*)&Cs[r * SA_C + seg * 8];
    }
}

// ---------------------------------------------------------------------------
// MK2: up -> (+x_ji) cat -> rb0a -> rb0b(+state) -> lin(+e1f_old, state=) ->
//      ra0a -> ra0b(+state) -> ra1a -> ra1b(+state) -> write e1f, e1b
// ---------------------------------------------------------------------------
__global__ __launch_bounds__(256)
void mk2(const unsigned short* __restrict__ bufD, const unsigned short* __restrict__ buf1g,
         float* __restrict__ e1f, unsigned short* __restrict__ e1b,
         const unsigned short* __restrict__ w_up, const unsigned short* __restrict__ w_cat,
         const unsigned short* __restrict__ w_rb0, const unsigned short* __restrict__ w_rb1,
         const unsigned short* __restrict__ w_lin,
         const unsigned short* __restrict__ w_ra0, const unsigned short* __restrict__ w_ra1,
         const unsigned short* __restrict__ w_ra2, const unsigned short* __restrict__ w_ra3,
         const float* __restrict__ b_rb0, const float* __restrict__ b_rb1,
         const float* __restrict__ b_lin,
         const float* __restrict__ b_ra0, const float* __restrict__ b_ra1,
         const float* __restrict__ b_ra2, const float* __restrict__ b_ra3) {
    __shared__ unsigned short Cs[128 * SA_C];
    __shared__ unsigned short Bs[128 * SA_B];

    const int tid = threadIdx.x;
    const size_t row0 = (size_t)blockIdx.x * 128;
    const int lane = tid & 63, wave = tid >> 6, lm = lane & 15, quad = lane >> 4;
    const int rw0 = (wave >> 1) * 64, cw0 = (wave & 1) * 64;

    f32x4 acc[4][4], state[4][4];
    uint4 wreg[4];

#define K128_START(WCUR, WNEXT)                          \
    zero_acc(acc);                                       \
    loadW<4>(wreg, (WCUR), 128, 64, tid);                \
    mfma_chunk(Cs, 0, Bs, lm, quad, rw0, cw0, acc);      \
    __syncthreads();                                     \
    storeW<4>(wreg, Bs, tid);                            \
    __syncthreads();                                     \
    loadW<4>(wreg, (WNEXT), 128, 0, tid);                \
    mfma_chunk(Cs, 64, Bs, lm, quad, rw0, cw0, acc);     \
    __syncthreads();

#define TILE_LOOP(PRELOAD, BODY, POST)                          \
    _Pragma("unroll") for (int mi = 0; mi < 4; ++mi) {          \
      const int f0 = rw0 + mi * 16 + quad * 4;                  \
      _Pragma("unroll") for (int ni = 0; ni < 4; ++ni) {        \
        const int m = cw0 + ni * 16 + lm;                       \
        const size_t goff = (size_t)(row0 + m) * 128 + f0;      \
        (void)goff;                                             \
        PRELOAD                                                 \
        float v4[4];                                            \
        _Pragma("unroll") for (int r = 0; r < 4; ++r) { BODY }  \
        st4(Cs, m, f0, v4);                                     \
        POST } }

    // initial staging: Cs <- bufD tile (K=64), Bs <- Wup (K=64 full)
    for (int i = tid; i < 128 * 8; i += 256) {
        int r = i >> 3, seg = i & 7;
        *(uint4*)&Cs[r * SA_C + seg * 8] = *(const uint4*)(bufD + (row0 + r) * 64 + seg * 8);
    }
    loadW<4>(wreg, w_up, 64, 0, tid); storeW<4>(wreg, Bs, tid);
    __syncthreads();

    // ---- up (K=64, no bias): Cs = bf16(x_ji + bf16(silu(acc))) ----
    zero_acc(acc);
    loadW<4>(wreg, w_cat, 128, 0, tid);
    mfma_chunk(Cs, 0, Bs, lm, quad, rw0, cw0, acc);
    __syncthreads();
    TILE_LOOP(
        ushort4 xj = *(const ushort4*)(buf1g + goff);,
        { float v = silu_f(acc[mi][ni][r]);
          v4[r] = b2f((&xj.x)[r]) + b2f(f2b(v)); },
    )
    storeW<4>(wreg, Bs, tid);
    __syncthreads();

    // ---- cat (no bias): state = silu(acc) ----
    K128_START(w_cat, w_rb0)
    TILE_LOOP(,
        { float v = silu_f(acc[mi][ni][r]); state[mi][ni][r] = v; v4[r] = v; },
    )
    storeW<4>(wreg, Bs, tid);
    __syncthreads();

    // ---- rb0a ----
    K128_START(w_rb0, w_rb1)
    TILE_LOOP(
        float4 b4 = *(const float4*)(b_rb0 + f0);,
        { v4[r] = silu_f(acc[mi][ni][r] + (&b4.x)[r]); },
    )
    storeW<4>(wreg, Bs, tid);
    __syncthreads();

    // ---- rb0b: state += silu ----
    K128_START(w_rb1, w_lin)
    TILE_LOOP(
        float4 b4 = *(const float4*)(b_rb1 + f0);,
        { float v = state[mi][ni][r] + silu_f(acc[mi][ni][r] + (&b4.x)[r]);
          state[mi][ni][r] = v; v4[r] = v; },
    )
    storeW<4>(wreg, Bs, tid);
    __syncthreads();

    // ---- lin: state = silu(acc+b) + e1f_old ----
    K128_START(w_lin, w_ra0)
    TILE_LOOP(
        float4 b4 = *(const float4*)(b_lin + f0);
        float4 e4 = *(const float4*)(e1f + goff);,
        { float v = silu_f(acc[mi][ni][r] + (&b4.x)[r]) + (&e4.x)[r];
          state[mi][ni][r] = v; v4[r] = v; },
    )
    storeW<4>(wreg, Bs, tid);
    __syncthreads();

    // ---- ra0a ----
    K128_START(w_ra0, w_ra1)
    TILE_LOOP(
        float4 b4 = *(const float4*)(b_ra0 + f0);,
        { v4[r] = silu_f(acc[mi][ni][r] + (&b4.x)[r]); },
    )
    storeW<4>(wreg, Bs, tid);
    __syncthreads();

    // ---- ra0b: state += silu ----
    K128_START(w_ra1, w_ra2)
    TILE_LOOP(
        float4 b4 = *(const float4*)(b_ra1 + f0);,
        { float v = state[mi][ni][r] + silu_f(acc[mi][ni][r] + (&b4.x)[r]);
          state[mi][ni][r] = v; v4[r] = v; },
    )
    storeW<4>(wreg, Bs, tid);
    __syncthreads();

    // ---- ra1a ----
    K128_START(w_ra2, w_ra3)
    TILE_LOOP(
        float4 b4 = *(const float4*)(b_ra2 + f0);,
        { v4[r] = silu_f(acc[mi][ni][r] + (&b4.x)[r]); },
    )
    storeW<4>(wreg, Bs, tid);
    __syncthreads();

    // ---- ra1b: state += silu; write e1f (fp32) + Cs for e1b copy ----
    K128_START(w_ra3, w_ra3)
    TILE_LOOP(
        float4 b4 = *(const float4*)(b_ra3 + f0);,
        { float v = state[mi][ni][r] + silu_f(acc[mi][ni][r] + (&b4.x)[r]);
          state[mi][ni][r] = v; v4[r] = v; },
        { float4 ev; ev.x = v4[0]; ev.y = v4[1]; ev.z = v4[2]; ev.w = v4[3];
          *(float4*)(e1f + goff) = ev; }
    )
    __syncthreads();
    for (int i = tid; i < 128 * 16; i += 256) {
        int r = i >> 4, seg = i & 15;
        *(uint4*)(e1b + (row0 + r) * 128 + seg * 8) = *(const uint4*)&Cs[r * SA_C + seg * 8];
    }
#undef K128_START
#undef TILE_LOOP
}

// weight transpose+bf16: src fp32 [B,K,N] -> dst bf16 [B,N,K]
__global__ void transpose_w(const float* __restrict__ src, unsigned short* __restrict__ dst,
                            int B, int K, int N) {
    size_t total = (size_t)B * K * N;
    size_t i = (size_t)blockIdx.x * 256 + threadIdx.x;
    if (i >= total) return;
    int b = i / ((size_t)K * N);
    size_t rem = i - (size_t)b * K * N;
    int k = rem / N, n = rem % N;
    dst[(size_t)b * K * N + (size_t)n * K + k] = f2b(src[i]);
}

// ---------------------------------------------------------------------------
// fp32 GEMM (node pipeline + input projections), optional bf16 output copy
// ---------------------------------------------------------------------------
template <int K>
__launch_bounds__(256)
__global__ void gemm_k(const float* __restrict__ A, const float* __restrict__ W,
                       const float* __restrict__ bias, float* __restrict__ out,
                       unsigned short* __restrict__ outb, int N, int act) {
    constexpr int KC = (K <= 128) ? K : 128;
    __shared__ float As[32][KC + 1];
    __shared__ float Ws[KC * 64];
    const int tid = threadIdx.x;
    const size_t row0 = (size_t)blockIdx.x * 32;
    const int tx = tid & 15, ty = tid >> 4;
    const int c0 = tx * 4, r0 = ty * 2;

    for (int nc0 = 0; nc0 < N; nc0 += 64) {
        float acc[2][4] = {{0.f, 0.f, 0.f, 0.f}, {0.f, 0.f, 0.f, 0.f}};
        for (int kc0 = 0; kc0 < K; kc0 += KC) {
            __syncthreads();
            for (int idx = tid; idx < 32 * KC / 4; idx += 256) {
                int r = idx / (KC / 4);
                int kk = (idx % (KC / 4)) * 4;
                float4 v = *(const float4*)(A + (row0 + r) * K + kc0 + kk);
                As[r][kk] = v.x; As[r][kk + 1] = v.y;
                As[r][kk + 2] = v.z; As[r][kk + 3] = v.w;
            }
            for (int idx = tid; idx < KC * 16; idx += 256) {
                int k = idx >> 4;
                int cc = (idx & 15) * 4;
                *(float4*)&Ws[k * 64 + cc] =
                    *(const float4*)(W + (size_t)(kc0 + k) * N + nc0 + cc);
            }
            __syncthreads();
#pragma unroll 4
            for (int k = 0; k < KC; ++k) {
                float a0 = As[r0][k], a1 = As[r0 + 1][k];
                float4 w = *(const float4*)&Ws[k * 64 + c0];
                acc[0][0] += a0 * w.x; acc[0][1] += a0 * w.y;
                acc[0][2] += a0 * w.z; acc[0][3] += a0 * w.w;
                acc[1][0] += a1 * w.x; acc[1][1] += a1 * w.y;
                acc[1][2] += a1 * w.z; acc[1][3] += a1 * w.w;
            }
        }
#pragma unroll
        for (int i = 0; i < 2; ++i) {
            size_t off = (row0 + r0 + i) * N + nc0 + c0;
            float4 v = make_float4(acc[i][0], acc[i][1], acc[i][2], acc[i][3]);
            if (bias) {
                float4 b = *(const float4*)(bias + nc0 + c0);
                v.x += b.x; v.y += b.y; v.z += b.z; v.w += b.w;
            }
            if (act) {
                v.x = silu_f(v.x); v.y = silu_f(v.y);
                v.z = silu_f(v.z); v.w = silu_f(v.w);
            }
            if (out) *(float4*)(out + off) = v;
            if (outb) {
                ushort4 u = make_ushort4(f2b(v.x), f2b(v.y), f2b(v.z), f2b(v.w));
                *(ushort4*)(outb + off) = u;
            }
        }
    }
}

__global__ void combine_rbf(const float* __restrict__ W1, const float* __restrict__ W2,
                            float* __restrict__ C) {
    int l = blockIdx.x;
    const float* w1 = W1 + l * 48;
    const float* w2 = W2 + l * 1024;
    float* c = C + l * 768;
    for (int idx = threadIdx.x; idx < 768; idx += 256) {
        int j = idx >> 7, h = idx & 127;
        float s = 0.f;
#pragma unroll
        for (int p = 0; p < 8; ++p) s += w1[j * 8 + p] * w2[p * 128 + h];
        c[idx] = s;
    }
}

// ------------------------- CSR build -------------------------
__global__ void hist_kernel(const int* __restrict__ idx, int n, int* __restrict__ cnt) {
    int t = blockIdx.x * 256 + threadIdx.x;
    if (t < n) atomicAdd(&cnt[idx[t]], 1);
}

__launch_bounds__(1024)
__global__ void scan1(const int* __restrict__ cnt, int n, int* __restrict__ offs,
                      int* __restrict__ partials) {
    __shared__ int tmp[1024];
    int tid = threadIdx.x;
    int i = blockIdx.x * 1024 + tid;
    int v = (i < n) ? cnt[i] : 0;
    tmp[tid] = v; __syncthreads();
    for (int d = 1; d < 1024; d <<= 1) {
        int t = (tid >= d) ? tmp[tid - d] : 0; __syncthreads();
        tmp[tid] += t; __syncthreads();
    }
    if (i < n) offs[i] = tmp[tid] - v;
    if (tid == 1023) partials[blockIdx.x] = tmp[1023];
}

__launch_bounds__(1024)
__global__ void scan2(int* __restrict__ partials, int nb, int n, int* __restrict__ offs) {
    __shared__ int tmp[1024];
    int tid = threadIdx.x;
    int v = (tid < nb) ? partials[tid] : 0;
    tmp[tid] = v; __syncthreads();
    for (int d = 1; d < 1024; d <<= 1) {
        int t = (tid >= d) ? tmp[tid - d] : 0; __syncthreads();
        tmp[tid] += t; __syncthreads();
    }
    if (tid < nb) partials[tid] = tmp[tid] - v;
    if (tid == 1023) offs[n] = tmp[1023];
}

__launch_bounds__(1024)
__global__ void scan3(int n, int* __restrict__ offs, const int* __restrict__ partials,
                      int* __restrict__ cur) {
    int i = blockIdx.x * 1024 + threadIdx.x;
    if (i < n) { int o = offs[i] + partials[blockIdx.x]; offs[i] = o; cur[i] = o; }
}

__global__ void fill_kernel(const int* __restrict__ idx, int n,
                            int* __restrict__ cur, int* __restrict__ lst) {
    int t = blockIdx.x * 256 + threadIdx.x;
    if (t < n) {
        int p = atomicAdd(&cur[idx[t]], 1);
        lst[p] = t;
    }
}

// ------------------------ triplet stage ------------------------
__launch_bounds__(128)
__global__ void p8_kernel(const float* __restrict__ sbf, const float* __restrict__ W1,
                          float* __restrict__ p8) {
    __shared__ float S[128 * 43];
    __shared__ float Wl[SBF_DIM * 8];
    int tid = threadIdx.x;
    for (int i = tid; i < SBF_DIM * 8; i += 128) Wl[i] = W1[i];
    size_t base = (size_t)blockIdx.x * 128;
    int rows = (TT - base) < 128 ? (int)(TT - base) : 128;
    const float* src = sbf + base * SBF_DIM;
    for (int i = tid; i < rows * SBF_DIM; i += 128) {
        int r = i / SBF_DIM, j = i - r * SBF_DIM;
        S[r * 43 + j] = src[i];
    }
    __syncthreads();
    if (tid >= rows) return;
    float pv[8] = {0.f, 0.f, 0.f, 0.f, 0.f, 0.f, 0.f, 0.f};
    for (int j = 0; j < SBF_DIM; ++j) {
        float sv = S[tid * 43 + j];
#pragma unroll
        for (int p = 0; p < 8; ++p) pv[p] += sv * Wl[j * 8 + p];
    }
    float4* o = (float4*)(p8 + (base + tid) * 8);
    o[0] = make_float4(pv[0], pv[1], pv[2], pv[3]);
    o[1] = make_float4(pv[4], pv[5], pv[6], pv[7]);
}

__launch_bounds__(256)
__global__ void triplet_gather(const float* __restrict__ p8, const float* __restrict__ W2,
                               const unsigned short* __restrict__ xkj,
                               const int* __restrict__ idx_kj,
                               const int* __restrict__ offsT, const int* __restrict__ tlist,
                               unsigned short* __restrict__ agg) {
    int lane = threadIdx.x & 63;
    int wv = threadIdx.x >> 6;
    int e = blockIdx.x * 4 + wv;
    if (e >= EE) return;
    float w2c[8];
#pragma unroll
    for (int p = 0; p < 8; ++p) w2c[p] = W2[p * INTD + lane];
    int b = offsT[e], en = offsT[e + 1];
    float acc = 0.f;
    for (int q = b; q < en; ++q) {
        int t = tlist[q];
        int k = idx_kj[t];
        const float4* pr = (const float4*)(p8 + (size_t)t * 8);
        float4 p0 = pr[0], p1 = pr[1];
        float s = p0.x * w2c[0] + p0.y * w2c[1] + p0.z * w2c[2] + p0.w * w2c[3]
                + p1.x * w2c[4] + p1.y * w2c[5] + p1.z * w2c[6] + p1.w * w2c[7];
        acc += s * b2f(xkj[(size_t)k * INTD + lane]);
    }
    agg[(size_t)e * INTD + lane] = f2b(acc);
}

__launch_bounds__(256)
__global__ void e2_gather(const float* __restrict__ rbf, const float* __restrict__ Wr,
                          const float* __restrict__ e1f, const int* __restrict__ offsE,
                          const int* __restrict__ elist, float* __restrict__ vseg) {
    int h = threadIdx.x & 127;
    int sub = threadIdx.x >> 7;
    int n = blockIdx.x * 2 + sub;
    if (n >= NN) return;
    float c0 = Wr[0 * 128 + h], c1 = Wr[1 * 128 + h], c2 = Wr[2 * 128 + h],
          c3 = Wr[3 * 128 + h], c4 = Wr[4 * 128 + h], c5 = Wr[5 * 128 + h];
    int b = offsE[n], en = offsE[n + 1];
    float a0 = 0.f, a1 = 0.f, a2 = 0.f, a3 = 0.f;
    int q = b;
    for (; q + 4 <= en; q += 4) {
        int ea = elist[q], eb = elist[q + 1], ec = elist[q + 2], ed = elist[q + 3];
        const float* ra = rbf + (size_t)ea * NRAD;
        const float* rb = rbf + (size_t)eb * NRAD;
        const float* rc = rbf + (size_t)ec * NRAD;
        const float* rd = rbf + (size_t)ed * NRAD;
        float fa = e1f[(size_t)ea * 128 + h];
        float fb = e1f[(size_t)eb * 128 + h];
        float fc = e1f[(size_t)ec * 128 + h];
        float fd = e1f[(size_t)ed * 128 + h];
        float sa = ra[0] * c0 + ra[1] * c1 + ra[2] * c2 + ra[3] * c3 + ra[4] * c4 + ra[5] * c5;
        float sb = rb[0] * c0 + rb[1] * c1 + rb[2] * c2 + rb[3] * c3 + rb[4] * c4 + rb[5] * c5;
        float sc = rc[0] * c0 + rc[1] * c1 + rc[2] * c2 + rc[3] * c3 + rc[4] * c4 + rc[5] * c5;
        float sd = rd[0] * c0 + rd[1] * c1 + rd[2] * c2 + rd[3] * c3 + rd[4] * c4 + rd[5] * c5;
        a0 += sa * fa; a1 += sb * fb; a2 += sc * fc; a3 += sd * fd;
    }
    for (; q < en; ++q) {
        int e = elist[q];
        const float* rr = rbf + (size_t)e * NRAD;
        float s = rr[0] * c0 + rr[1] * c1 + rr[2] * c2 + rr[3] * c3 + rr[4] * c4 + rr[5] * c5;
        a0 += s * e1f[(size_t)e * 128 + h];
    }
    vseg[(size_t)n * 128 + h] = (a0 + a1) + (a2 + a3);
}

__global__ void scatter_u0(const float* __restrict__ v, const int* __restrict__ batch,
                           float* __restrict__ u0) {
    int idx = blockIdx.x * 256 + threadIdx.x;
    int h = idx & 127;
    int n = idx >> 7;
    atomicAdd(&u0[(size_t)batch[n] * 128 + h], v[idx]);
}

__launch_bounds__(256)
__global__ void vout_scatter(const float* __restrict__ vn, const float* __restrict__ Wv_out,
                             const int* __restrict__ batch, float* __restrict__ sbatch) {
    int wave = threadIdx.x >> 6, lane = threadIdx.x & 63;
    int n = blockIdx.x * 4 + wave;
    if (n >= NN) return;
    const float* row = vn + (size_t)n * OUT_EMB;
    float s = 0.f;
#pragma unroll
    for (int k = lane; k < OUT_EMB; k += 64) s += row[k] * Wv_out[k];
#pragma unroll
    for (int off = 32; off > 0; off >>= 1) s += __shfl_down(s, off);
    if (lane == 0) atomicAdd(&sbatch[batch[n]], s);
}

__global__ void final_out(const float* __restrict__ u0, const float* __restrict__ sb,
                          float* __restrict__ out) {
    int idx = blockIdx.x * 256 + threadIdx.x;
    out[idx] = u0[idx] + sb[idx >> 7];
}

extern "C" void kernel_launch(void* const* d_in, const int* in_sizes, int n_in,
                              void* d_out, int out_size, void* d_ws, size_t ws_size,
                              hipStream_t stream) {
    const float* x         = (const float*)d_in[0];
    const float* edge_attr = (const float*)d_in[1];
    const float* rbf       = (const float*)d_in[2];
    const float* sbf       = (const float*)d_in[3];
    const int*   iidx      = (const int*)d_in[4];
    const int*   idx_kj    = (const int*)d_in[5];
    const int*   idx_ji    = (const int*)d_in[6];
    const int*   batch     = (const int*)d_in[7];
    const float* W_node    = (const float*)d_in[8];
    const float* W_edge    = (const float*)d_in[9];
    const float* We_rbf1   = (const float*)d_in[10];
    const float* We_rbf2   = (const float*)d_in[11];
    const float* We_sbf1   = (const float*)d_in[12];
    const float* We_sbf2   = (const float*)d_in[13];
    const float* We_rbf    = (const float*)d_in[14];
    const float* We_kj     = (const float*)d_in[15];
    const float* be_kj     = (const float*)d_in[16];
    const float* We_ji     = (const float*)d_in[17];
    const float* be_ji     = (const float*)d_in[18];
    const float* We_down   = (const float*)d_in[19];
    const float* We_up     = (const float*)d_in[20];
    const float* We_cat    = (const float*)d_in[21];
    const float* Wres_b    = (const float*)d_in[22];
    const float* bres_b    = (const float*)d_in[23];
    const float* We_lin    = (const float*)d_in[24];
    const float* be_lin    = (const float*)d_in[25];
    const float* Wres_a    = (const float*)d_in[26];
    const float* bres_a    = (const float*)d_in[27];
    const float* Wv_up     = (const float*)d_in[28];
    const float* bv_up     = (const float*)d_in[29];
    const float* Wv_lins   = (const float*)d_in[30];
    const float* bv_lins   = (const float*)d_in[31];
    const float* Wv_out    = (const float*)d_in[32];
    float* out = (float*)d_out;

    // ---- workspace layout ----
    unsigned short* e1b  = (unsigned short*)d_ws;            // E*128 bf16
    unsigned short* buf1 = e1b  + (size_t)EE * HH;           // E*128 bf16 (x_ji)
    unsigned short* scr2 = buf1 + (size_t)EE * HH;           // E*128 slot (p8 alias)
    unsigned short* bufC = scr2 + (size_t)EE * HH;           // E*64 bf16 (xkj_down)
    unsigned short* bufD = bufC + (size_t)EE * INTD;         // E*64 bf16 (agg)
    unsigned short* endu = bufD + (size_t)EE * INTD;
    float* e1f    = (float*)endu;                            // E*128 fp32 master
    float* tail   = e1f + (size_t)EE * HH;
    float* u0     = tail;                                    // B*128
    float* sbatch = u0 + BB * HH;                            // 256
    float* Crbf   = sbatch + 256;                            // 4*768
    int*   iptr   = (int*)(Crbf + 4 * 768);
    int* cntT  = iptr;               iptr += EE;
    int* offsT = iptr;               iptr += EE + 1;
    int* curT  = iptr;               iptr += EE;
    int* tlist = iptr;               iptr += TT;
    int* cntE  = iptr;               iptr += NN;
    int* offsE = iptr;               iptr += NN + 1;
    int* curE  = iptr;               iptr += NN;
    int* elist = iptr;               iptr += EE;
    int* partials = iptr;            iptr += 1024;
    unsigned short* wptr = (unsigned short*)iptr;
    unsigned short* wt_ji   = wptr;  wptr += 4 * 16384;
    unsigned short* wt_kj   = wptr;  wptr += 4 * 16384;
    unsigned short* wt_down = wptr;  wptr += 4 * 8192;
    unsigned short* wt_up   = wptr;  wptr += 4 * 8192;
    unsigned short* wt_cat  = wptr;  wptr += 4 * 16384;
    unsigned short* wt_resb = wptr;  wptr += 8 * 16384;
    unsigned short* wt_lin  = wptr;  wptr += 4 * 16384;
    unsigned short* wt_resa = wptr;  wptr += 16 * 16384;
    float* p8 = (float*)scr2;                                // [T,8] fp32
    float* vseg = (float*)bufC;                              // N*128 fp32 (post-MK2)
    float* vn1  = vseg + (size_t)NN * HH;                    // N*256
    float* vn2  = vn1 + (size_t)NN * OUT_EMB;                // N*256

    hipMemsetAsync(u0, 0, (size_t)BB * HH * sizeof(float), stream);
    hipMemsetAsync(sbatch, 0, 256 * sizeof(float), stream);
    combine_rbf<<<4, 256, 0, stream>>>(We_rbf1, We_rbf2, Crbf);

    transpose_w<<<(4 * 16384 + 255) / 256, 256, 0, stream>>>(We_ji, wt_ji, 4, 128, 128);
    transpose_w<<<(4 * 16384 + 255) / 256, 256, 0, stream>>>(We_kj, wt_kj, 4, 128, 128);
    transpose_w<<<(4 * 8192 + 255) / 256, 256, 0, stream>>>(We_down, wt_down, 4, 128, 64);
    transpose_w<<<(4 * 8192 + 255) / 256, 256, 0, stream>>>(We_up, wt_up, 4, 64, 128);
    transpose_w<<<(4 * 16384 + 255) / 256, 256, 0, stream>>>(We_cat, wt_cat, 4, 128, 128);
    transpose_w<<<(8 * 16384 + 255) / 256, 256, 0, stream>>>(Wres_b, wt_resb, 8, 128, 128);
    transpose_w<<<(4 * 16384 + 255) / 256, 256, 0, stream>>>(We_lin, wt_lin, 4, 128, 128);
    transpose_w<<<(16 * 16384 + 255) / 256, 256, 0, stream>>>(Wres_a, wt_resa, 16, 128, 128);

    hipMemsetAsync(cntT, 0, EE * sizeof(int), stream);
    hipMemsetAsync(cntE, 0, NN * sizeof(int), stream);
    hist_kernel<<<(TT + 255) / 256, 256, 0, stream>>>(idx_ji, TT, cntT);
    hist_kernel<<<(EE + 255) / 256, 256, 0, stream>>>(iidx, EE, cntE);
    int nbT = (EE + 1023) / 1024, nbE = (NN + 1023) / 1024;
    scan1<<<nbT, 1024, 0, stream>>>(cntT, EE, offsT, partials);
    scan2<<<1, 1024, 0, stream>>>(partials, nbT, EE, offsT);
    scan3<<<nbT, 1024, 0, stream>>>(EE, offsT, partials, curT);
    fill_kernel<<<(TT + 255) / 256, 256, 0, stream>>>(idx_ji, TT, curT, tlist);
    scan1<<<nbE, 1024, 0, stream>>>(cntE, NN, offsE, partials);
    scan2<<<1, 1024, 0, stream>>>(partials, nbE, NN, offsE);
    scan3<<<nbE, 1024, 0, stream>>>(NN, offsE, partials, curE);
    fill_kernel<<<(EE + 255) / 256, 256, 0, stream>>>(iidx, EE, curE, elist);

    gemm_k<12><<<EE / 32, 256, 0, stream>>>(edge_attr, W_edge, nullptr, e1f, e1b, HH, 0);
    gemm_k<48><<<NN / 32, 256, 0, stream>>>(x, W_node, nullptr, vseg, nullptr, HH, 0);
    scatter_u0<<<NN * HH / 256, 256, 0, stream>>>(vseg, batch, u0);

    const int GR = EE / 128;  // 3125
    for (int l = 0; l < 4; ++l) {
        mk1<<<GR, 256, 0, stream>>>(e1b, wt_ji + l * 16384, wt_kj + l * 16384,
                                    wt_down + l * 8192, be_ji + l * HH, be_kj + l * HH,
                                    rbf, Crbf + l * 768, buf1, bufC);
        p8_kernel<<<(TT + 127) / 128, 128, 0, stream>>>(sbf, We_sbf1 + l * SBF_DIM * 8, p8);
        triplet_gather<<<EE / 4, 256, 0, stream>>>(p8, We_sbf2 + l * 8 * INTD, bufC,
                                                   idx_kj, offsT, tlist, bufD);
        mk2<<<GR, 256, 0, stream>>>(bufD, buf1, e1f, e1b,
            wt_up + l * 8192, wt_cat + l * 16384,
            wt_resb + (l * 2 + 0) * 16384, wt_resb + (l * 2 + 1) * 16384,
            wt_lin + l * 16384,
            wt_resa + ((l * 2 + 0) * 2 + 0) * 16384, wt_resa + ((l * 2 + 0) * 2 + 1) * 16384,
            wt_resa + ((l * 2 + 1) * 2 + 0) * 16384, wt_resa + ((l * 2 + 1) * 2 + 1) * 16384,
            bres_b + (l * 2 + 0) * HH, bres_b + (l * 2 + 1) * HH, be_lin + l * HH,
            bres_a + ((l * 2 + 0) * 2 + 0) * HH, bres_a + ((l * 2 + 0) * 2 + 1) * HH,
            bres_a + ((l * 2 + 1) * 2 + 0) * HH, bres_a + ((l * 2 + 1) * 2 + 1) * HH);
        e2_gather<<<(NN + 1) / 2, 256, 0, stream>>>(rbf, We_rbf + (size_t)l * NRAD * HH,
                                                    e1f, offsE, elist, vseg);
        gemm_k<128><<<NN / 32, 256, 0, stream>>>(vseg, Wv_up + (size_t)l * HH * OUT_EMB,
                                                 bv_up + l * OUT_EMB, vn1, nullptr, OUT_EMB, 0);
        gemm_k<256><<<NN / 32, 256, 0, stream>>>(vn1, Wv_lins + (size_t)(l * 3 + 0) * 65536,
                                                 bv_lins + (l * 3 + 0) * 256, vn2, nullptr, OUT_EMB, 1);
        gemm_k<256><<<NN / 32, 256, 0, stream>>>(vn2, Wv_lins + (size_t)(l * 3 + 1) * 65536,
                                                 bv_lins + (l * 3 + 1) * 256, vn1, nullptr, OUT_EMB, 1);
        gemm_k<256><<<NN / 32, 256, 0, stream>>>(vn1, Wv_lins + (size_t)(l * 3 + 2) * 65536,
                                                 bv_lins + (l * 3 + 2) * 256, vn2, nullptr, OUT_EMB, 1);
        vout_scatter<<<NN / 4, 256, 0, stream>>>(vn2, Wv_out + l * OUT_EMB, batch, sbatch);
    }
    final_out<<<BB * HH / 256, 256, 0, stream>>>(u0, sbatch, out);
}

// Round 3
// 6904.626 us; speedup vs baseline: 1.1847x; 1.1587x over previous
//
#include <hip/hip_runtime.h>
#include <hip/hip_bf16.h>
#include <cstddef>

#define NN 20000
#define EE 400000
#define TT 1500000
#define BB 128
#define HH 128
#define INTD 64
#define OUT_EMB 256
#define SBF_DIM 42
#define NRAD 6

#define SA_C 136   // LDS row stride (ushorts): 272B, 16B-aligned, 2-way bank (free)

typedef __attribute__((ext_vector_type(8))) short bf16x8;
typedef __attribute__((ext_vector_type(4))) float f32x4;

__device__ __forceinline__ float silu_f(float v) {
    return v / (1.0f + __expf(-v));
}
__device__ __forceinline__ unsigned short f2b(float f) {
    __hip_bfloat16 h = __float2bfloat16(f);
    unsigned short u; __builtin_memcpy(&u, &h, 2); return u;
}
__device__ __forceinline__ float b2f(unsigned short u) {
    __hip_bfloat16 h; __builtin_memcpy(&h, &u, 2); return __bfloat162float(h);
}

// --- async weight staging: global->reg (issue early), reg->LDS (after barrier) ---
// W is row-major [rows][K] contiguous; linear load. 512 threads.
template <int NU4>
__device__ __forceinline__ void loadWlin(uint4 (&rg)[NU4], const unsigned short* W, int tid) {
#pragma unroll
    for (int j = 0; j < NU4; ++j) rg[j] = *(const uint4*)(W + ((size_t)tid + j * 512) * 8);
}
// SEGS = uint4 per row (16 for K=128, 8 for K=64)
template <int NU4, int SEGS>
__device__ __forceinline__ void storeWs(const uint4 (&rg)[NU4], unsigned short* Ws, int tid) {
#pragma unroll
    for (int j = 0; j < NU4; ++j) {
        int i = tid + j * 512;
        int n = i / SEGS, seg = i % SEGS;
        *(uint4*)&Ws[n * SA_C + seg * 8] = rg[j];
    }
}

// packed epilogue store: 4 consecutive features of one edge row -> ds_write_b64
__device__ __forceinline__ void st4(unsigned short* Cs, int m, int f0, const float* v) {
    ushort4 u = make_ushort4(f2b(v[0]), f2b(v[1]), f2b(v[2]), f2b(v[3]));
    *(ushort4*)&Cs[m * SA_C + f0] = u;
}

// Operand-swapped wave tile 32(feat) x 64(edge): A = W^T rows (from Ws),
// B = X rows (edges, from Cs). Output: row = feature (quad*4+r), col = edge (lm).
template <int KCNT>
__device__ __forceinline__ void mfma_f(const unsigned short* Cs, const unsigned short* Ws,
                                       int lm, int quad, int fw0, int ew0, f32x4 acc[2][4]) {
#pragma unroll
    for (int kc = 0; kc < KCNT; ++kc) {
        bf16x8 wf[2], xf[4];
#pragma unroll
        for (int mi = 0; mi < 2; ++mi)
            wf[mi] = *(const bf16x8*)&Ws[(fw0 + mi * 16 + lm) * SA_C + kc * 32 + quad * 8];
#pragma unroll
        for (int ni = 0; ni < 4; ++ni)
            xf[ni] = *(const bf16x8*)&Cs[(ew0 + ni * 16 + lm) * SA_C + kc * 32 + quad * 8];
#pragma unroll
        for (int mi = 0; mi < 2; ++mi)
#pragma unroll
            for (int ni = 0; ni < 4; ++ni)
                acc[mi][ni] = __builtin_amdgcn_mfma_f32_16x16x32_bf16(wf[mi], xf[ni], acc[mi][ni], 0, 0, 0);
    }
}

// down GEMM wave tile 32(dfeat) x 32(edge)
template <int KCNT>
__device__ __forceinline__ void mfma_d2(const unsigned short* Cs, const unsigned short* Ws,
                                        int lm, int quad, int fw0, int ew0, f32x4 acc[2][2]) {
#pragma unroll
    for (int kc = 0; kc < KCNT; ++kc) {
        bf16x8 wf[2], xf[2];
#pragma unroll
        for (int mi = 0; mi < 2; ++mi)
            wf[mi] = *(const bf16x8*)&Ws[(fw0 + mi * 16 + lm) * SA_C + kc * 32 + quad * 8];
#pragma unroll
        for (int ni = 0; ni < 2; ++ni)
            xf[ni] = *(const bf16x8*)&Cs[(ew0 + ni * 16 + lm) * SA_C + kc * 32 + quad * 8];
#pragma unroll
        for (int mi = 0; mi < 2; ++mi)
#pragma unroll
            for (int ni = 0; ni < 2; ++ni)
                acc[mi][ni] = __builtin_amdgcn_mfma_f32_16x16x32_bf16(wf[mi], xf[ni], acc[mi][ni], 0, 0, 0);
    }
}

// ---------------------------------------------------------------------------
// MK1 (512 threads, 8 waves): x_ji = silu(e1@Wji+bji) -> buf1 ;
//   x_kj = silu(e1@Wkj+bkj)*r ; bufC = silu(x_kjr @ Wdown)
// ---------------------------------------------------------------------------
__global__ __launch_bounds__(512, 2)
void mk1(const unsigned short* __restrict__ e1b,
         const unsigned short* __restrict__ w_ji, const unsigned short* __restrict__ w_kj,
         const unsigned short* __restrict__ w_down,
         const float* __restrict__ be_ji, const float* __restrict__ be_kj,
         const float* __restrict__ rbf, const float* __restrict__ Crbf_l,
         unsigned short* __restrict__ buf1, unsigned short* __restrict__ bufC) {
    __shared__ unsigned short Cs[128 * SA_C];
    __shared__ unsigned short Ws[128 * SA_C];
    __shared__ float rbfS[128 * 6];
    __shared__ float CrbfS[768];

    const int tid = threadIdx.x;
    const size_t row0 = (size_t)blockIdx.x * 128;
    const int lane = tid & 63, wave = tid >> 6, lm = lane & 15, quad = lane >> 4;
    const int rw0 = (wave >> 1) * 32;   // feature base (4 groups)
    const int cw0 = (wave & 1) * 64;    // edge base (2 groups)
    const int fw0d = (wave & 1) * 32;   // down: feature base (2 groups)
    const int ew0d = (wave >> 1) * 32;  // down: edge base (4 groups)

    uint4 wreg[4]; uint4 wregd[2];

    // initial staging: Cs <- e1b tile (full K=128), Ws <- Wji full, rbf+Crbf tiles
    for (int i = tid; i < 2048; i += 512) {
        int r = i >> 4, seg = i & 15;
        *(uint4*)&Cs[r * SA_C + seg * 8] = *(const uint4*)(e1b + (row0 + r) * 128 + seg * 8);
    }
    loadWlin<4>(wreg, w_ji, tid); storeWs<4, 16>(wreg, Ws, tid);
    for (int i = tid; i < 768; i += 512) { rbfS[i] = rbf[row0 * 6 + i]; CrbfS[i] = Crbf_l[i]; }
    __syncthreads();

    // ---- ji GEMM -> jreg (kept in registers) ----
    f32x4 jreg[2][4], acc[2][4];
#pragma unroll
    for (int mi = 0; mi < 2; ++mi)
#pragma unroll
        for (int ni = 0; ni < 4; ++ni) jreg[mi][ni] = (f32x4){0.f, 0.f, 0.f, 0.f};
    loadWlin<4>(wreg, w_kj, tid);
    mfma_f<4>(Cs, Ws, lm, quad, rw0, cw0, jreg);
    __syncthreads();
    storeWs<4, 16>(wreg, Ws, tid);
    __syncthreads();

    // ---- kj GEMM ----
#pragma unroll
    for (int mi = 0; mi < 2; ++mi)
#pragma unroll
        for (int ni = 0; ni < 4; ++ni) acc[mi][ni] = (f32x4){0.f, 0.f, 0.f, 0.f};
    loadWlin<2>(wregd, w_down, tid);   // Wdown [64][128] -> 1024 uint4
    mfma_f<4>(Cs, Ws, lm, quad, rw0, cw0, acc);
    __syncthreads();
    // epi kj: silu + bias, r-scale; packed writes overwrite Cs; stage Wdown
#pragma unroll
    for (int mi = 0; mi < 2; ++mi) {
        const int f0 = rw0 + mi * 16 + quad * 4;
        const float4 bb = *(const float4*)(be_kj + f0);
#pragma unroll
        for (int ni = 0; ni < 4; ++ni) {
            const int m = cw0 + ni * 16 + lm;
            float4 rv = {0.f, 0.f, 0.f, 0.f};
#pragma unroll
            for (int j = 0; j < 6; ++j) {
                float rb = rbfS[m * 6 + j];
                float4 c4 = *(const float4*)&CrbfS[j * 128 + f0];
                rv.x += rb * c4.x; rv.y += rb * c4.y; rv.z += rb * c4.z; rv.w += rb * c4.w;
            }
            float v4[4];
#pragma unroll
            for (int r = 0; r < 4; ++r) {
                float v = silu_f(acc[mi][ni][r] + (&bb.x)[r]);
                v4[r] = b2f(f2b(v)) * (&rv.x)[r];
            }
            st4(Cs, m, f0, v4);
        }
    }
    storeWs<2, 16>(wregd, Ws, tid);
    __syncthreads();

    // ---- down GEMM (output 64 dfeat x 128 edges) ----
    f32x4 accd[2][2];
#pragma unroll
    for (int mi = 0; mi < 2; ++mi)
#pragma unroll
        for (int ni = 0; ni < 2; ++ni) accd[mi][ni] = (f32x4){0.f, 0.f, 0.f, 0.f};
    mfma_d2<4>(Cs, Ws, lm, quad, fw0d, ew0d, accd);
    __syncthreads();
    // epi down -> Cs cols 0..63, packed
#pragma unroll
    for (int mi = 0; mi < 2; ++mi) {
        const int f0 = fw0d + mi * 16 + quad * 4;
#pragma unroll
        for (int ni = 0; ni < 2; ++ni) {
            const int m = ew0d + ni * 16 + lm;
            float v4[4];
#pragma unroll
            for (int r = 0; r < 4; ++r) v4[r] = silu_f(accd[mi][ni][r]);
            st4(Cs, m, f0, v4);
        }
    }
    __syncthreads();
    // coalesced copy Cs(128x64) -> bufC
    for (int i = tid; i < 1024; i += 512) {
        int r = i >> 3, seg = i & 7;
        *(uint4*)(bufC + (row0 + r) * 64 + seg * 8) = *(const uint4*)&Cs[r * SA_C + seg * 8];
    }
    __syncthreads();
    // epi ji -> Cs (packed), then coalesced copy -> buf1
#pragma unroll
    for (int mi = 0; mi < 2; ++mi) {
        const int f0 = rw0 + mi * 16 + quad * 4;
        const float4 bj = *(const float4*)(be_ji + f0);
#pragma unroll
        for (int ni = 0; ni < 4; ++ni) {
            const int m = cw0 + ni * 16 + lm;
            float v4[4];
#pragma unroll
            for (int r = 0; r < 4; ++r) v4[r] = silu_f(jreg[mi][ni][r] + (&bj.x)[r]);
            st4(Cs, m, f0, v4);
        }
    }
    __syncthreads();
    for (int i = tid; i < 2048; i += 512) {
        int r = i >> 4, seg = i & 15;
        *(uint4*)(buf1 + (row0 + r) * 128 + seg * 8) = *(const uint4*)&Cs[r * SA_C + seg * 8];
    }
}

// ---------------------------------------------------------------------------
// MK2 (512 threads, 8 waves): up -> (+x_ji) cat -> rb0a -> rb0b(+state) ->
//   lin(+e1f_old, state=) -> ra0a -> ra0b -> ra1a -> ra1b -> write e1f, e1b
// Full-K weight buffer: 2 barriers per GEMM phase.
// ---------------------------------------------------------------------------
__global__ __launch_bounds__(512, 2)
void mk2(const unsigned short* __restrict__ bufD, const unsigned short* __restrict__ buf1g,
         float* __restrict__ e1f, unsigned short* __restrict__ e1b,
         const unsigned short* __restrict__ w_up, const unsigned short* __restrict__ w_cat,
         const unsigned short* __restrict__ w_rb0, const unsigned short* __restrict__ w_rb1,
         const unsigned short* __restrict__ w_lin,
         const unsigned short* __restrict__ w_ra0, const unsigned short* __restrict__ w_ra1,
         const unsigned short* __restrict__ w_ra2, const unsigned short* __restrict__ w_ra3,
         const float* __restrict__ b_rb0, const float* __restrict__ b_rb1,
         const float* __restrict__ b_lin,
         const float* __restrict__ b_ra0, const float* __restrict__ b_ra1,
         const float* __restrict__ b_ra2, const float* __restrict__ b_ra3) {
    __shared__ unsigned short Cs[128 * SA_C];
    __shared__ unsigned short Ws[128 * SA_C];

    const int tid = threadIdx.x;
    const size_t row0 = (size_t)blockIdx.x * 128;
    const int lane = tid & 63, wave = tid >> 6, lm = lane & 15, quad = lane >> 4;
    const int rw0 = (wave >> 1) * 32, cw0 = (wave & 1) * 64;

    f32x4 acc[2][4], state[2][4];
    uint4 wreg[4];

#define ZERO_ACC()                                                 \
    _Pragma("unroll") for (int mi = 0; mi < 2; ++mi)               \
    _Pragma("unroll") for (int ni = 0; ni < 4; ++ni)               \
        acc[mi][ni] = (f32x4){0.f, 0.f, 0.f, 0.f};

#define TILE_LOOP(PRELOAD, BODY, POST)                          \
    _Pragma("unroll") for (int mi = 0; mi < 2; ++mi) {          \
      const int f0 = rw0 + mi * 16 + quad * 4;                  \
      _Pragma("unroll") for (int ni = 0; ni < 4; ++ni) {        \
        const int m = cw0 + ni * 16 + lm;                       \
        const size_t goff = (size_t)(row0 + m) * 128 + f0;      \
        (void)goff;                                             \
        PRELOAD                                                 \
        float v4[4];                                            \
        _Pragma("unroll") for (int r = 0; r < 4; ++r) { BODY }  \
        st4(Cs, m, f0, v4);                                     \
        POST } }

    // initial staging: Cs <- bufD tile (K=64), Ws <- Wup [128][64]
    for (int i = tid; i < 1024; i += 512) {
        int r = i >> 3, seg = i & 7;
        *(uint4*)&Cs[r * SA_C + seg * 8] = *(const uint4*)(bufD + (row0 + r) * 64 + seg * 8);
    }
    {
        uint4 wu[2];
        loadWlin<2>(wu, w_up, tid); storeWs<2, 8>(wu, Ws, tid);
    }
    __syncthreads();

    // ---- up (K=64, no bias): Cs = bf16(x_ji + bf16(silu(acc))) ----
    ZERO_ACC()
    loadWlin<4>(wreg, w_cat, tid);
    mfma_f<2>(Cs, Ws, lm, quad, rw0, cw0, acc);
    __syncthreads();
    TILE_LOOP(
        ushort4 xj = *(const ushort4*)(buf1g + goff);,
        { float v = silu_f(acc[mi][ni][r]);
          v4[r] = b2f((&xj.x)[r]) + b2f(f2b(v)); },
    )
    storeWs<4, 16>(wreg, Ws, tid);
    __syncthreads();

    // full-K phase: mfma -> sync -> epilogue + stage next W -> sync
#define PHASE_HEAD(WNEXT)                          \
    ZERO_ACC()                                     \
    loadWlin<4>(wreg, (WNEXT), tid);               \
    mfma_f<4>(Cs, Ws, lm, quad, rw0, cw0, acc);    \
    __syncthreads();

#define PHASE_TAIL()                               \
    storeWs<4, 16>(wreg, Ws, tid);                 \
    __syncthreads();

    // ---- cat (no bias): state = silu(acc) ----
    PHASE_HEAD(w_rb0)
    TILE_LOOP(,
        { float v = silu_f(acc[mi][ni][r]); state[mi][ni][r] = v; v4[r] = v; },
    )
    PHASE_TAIL()

    // ---- rb0a ----
    PHASE_HEAD(w_rb1)
    TILE_LOOP(
        float4 b4 = *(const float4*)(b_rb0 + f0);,
        { v4[r] = silu_f(acc[mi][ni][r] + (&b4.x)[r]); },
    )
    PHASE_TAIL()

    // ---- rb0b: state += silu ----
    PHASE_HEAD(w_lin)
    TILE_LOOP(
        float4 b4 = *(const float4*)(b_rb1 + f0);,
        { float v = state[mi][ni][r] + silu_f(acc[mi][ni][r] + (&b4.x)[r]);
          state[mi][ni][r] = v; v4[r] = v; },
    )
    PHASE_TAIL()

    // ---- lin: state = silu(acc+b) + e1f_old ----
    PHASE_HEAD(w_ra0)
    TILE_LOOP(
        float4 b4 = *(const float4*)(b_lin + f0);
        float4 e4 = *(const float4*)(e1f + goff);,
        { float v = silu_f(acc[mi][ni][r] + (&b4.x)[r]) + (&e4.x)[r];
          state[mi][ni][r] = v; v4[r] = v; },
    )
    PHASE_TAIL()

    // ---- ra0a ----
    PHASE_HEAD(w_ra1)
    TILE_LOOP(
        float4 b4 = *(const float4*)(b_ra0 + f0);,
        { v4[r] = silu_f(acc[mi][ni][r] + (&b4.x)[r]); },
    )
    PHASE_TAIL()

    // ---- ra0b: state += silu ----
    PHASE_HEAD(w_ra2)
    TILE_LOOP(
        float4 b4 = *(const float4*)(b_ra1 + f0);,
        { float v = state[mi][ni][r] + silu_f(acc[mi][ni][r] + (&b4.x)[r]);
          state[mi][ni][r] = v; v4[r] = v; },
    )
    PHASE_TAIL()

    // ---- ra1a ----
    PHASE_HEAD(w_ra3)
    TILE_LOOP(
        float4 b4 = *(const float4*)(b_ra2 + f0);,
        { v4[r] = silu_f(acc[mi][ni][r] + (&b4.x)[r]); },
    )
    PHASE_TAIL()

    // ---- ra1b (final): state += silu; write e1f (fp32) + Cs for e1b copy ----
    ZERO_ACC()
    mfma_f<4>(Cs, Ws, lm, quad, rw0, cw0, acc);
    __syncthreads();
    TILE_LOOP(
        float4 b4 = *(const float4*)(b_ra3 + f0);,
        { float v = state[mi][ni][r] + silu_f(acc[mi][ni][r] + (&b4.x)[r]);
          state[mi][ni][r] = v; v4[r] = v; },
        { float4 ev; ev.x = v4[0]; ev.y = v4[1]; ev.z = v4[2]; ev.w = v4[3];
          *(float4*)(e1f + goff) = ev; }
    )
    __syncthreads();
    for (int i = tid; i < 2048; i += 512) {
        int r = i >> 4, seg = i & 15;
        *(uint4*)(e1b + (row0 + r) * 128 + seg * 8) = *(const uint4*)&Cs[r * SA_C + seg * 8];
    }
#undef PHASE_HEAD
#undef PHASE_TAIL
#undef TILE_LOOP
#undef ZERO_ACC
}

// weight transpose+bf16: src fp32 [B,K,N] -> dst bf16 [B,N,K]
__global__ void transpose_w(const float* __restrict__ src, unsigned short* __restrict__ dst,
                            int B, int K, int N) {
    size_t total = (size_t)B * K * N;
    size_t i = (size_t)blockIdx.x * 256 + threadIdx.x;
    if (i >= total) return;
    int b = i / ((size_t)K * N);
    size_t rem = i - (size_t)b * K * N;
    int k = rem / N, n = rem % N;
    dst[(size_t)b * K * N + (size_t)n * K + k] = f2b(src[i]);
}

// ---------------------------------------------------------------------------
// fp32 GEMM (node pipeline + input projections), optional bf16 output copy
// ---------------------------------------------------------------------------
template <int K>
__launch_bounds__(256)
__global__ void gemm_k(const float* __restrict__ A, const float* __restrict__ W,
                       const float* __restrict__ bias, float* __restrict__ out,
                       unsigned short* __restrict__ outb, int N, int act) {
    constexpr int KC = (K <= 128) ? K : 128;
    __shared__ float As[32][KC + 1];
    __shared__ float Ws[KC * 64];
    const int tid = threadIdx.x;
    const size_t row0 = (size_t)blockIdx.x * 32;
    const int tx = tid & 15, ty = tid >> 4;
    const int c0 = tx * 4, r0 = ty * 2;

    for (int nc0 = 0; nc0 < N; nc0 += 64) {
        float acc[2][4] = {{0.f, 0.f, 0.f, 0.f}, {0.f, 0.f, 0.f, 0.f}};
        for (int kc0 = 0; kc0 < K; kc0 += KC) {
            __syncthreads();
            for (int idx = tid; idx < 32 * KC / 4; idx += 256) {
                int r = idx / (KC / 4);
                int kk = (idx % (KC / 4)) * 4;
                float4 v = *(const float4*)(A + (row0 + r) * K + kc0 + kk);
                As[r][kk] = v.x; As[r][kk + 1] = v.y;
                As[r][kk + 2] = v.z; As[r][kk + 3] = v.w;
            }
            for (int idx = tid; idx < KC * 16; idx += 256) {
                int k = idx >> 4;
                int cc = (idx & 15) * 4;
                *(float4*)&Ws[k * 64 + cc] =
                    *(const float4*)(W + (size_t)(kc0 + k) * N + nc0 + cc);
            }
            __syncthreads();
#pragma unroll 4
            for (int k = 0; k < KC; ++k) {
                float a0 = As[r0][k], a1 = As[r0 + 1][k];
                float4 w = *(const float4*)&Ws[k * 64 + c0];
                acc[0][0] += a0 * w.x; acc[0][1] += a0 * w.y;
                acc[0][2] += a0 * w.z; acc[0][3] += a0 * w.w;
                acc[1][0] += a1 * w.x; acc[1][1] += a1 * w.y;
                acc[1][2] += a1 * w.z; acc[1][3] += a1 * w.w;
            }
        }
#pragma unroll
        for (int i = 0; i < 2; ++i) {
            size_t off = (row0 + r0 + i) * N + nc0 + c0;
            float4 v = make_float4(acc[i][0], acc[i][1], acc[i][2], acc[i][3]);
            if (bias) {
                float4 b = *(const float4*)(bias + nc0 + c0);
                v.x += b.x; v.y += b.y; v.z += b.z; v.w += b.w;
            }
            if (act) {
                v.x = silu_f(v.x); v.y = silu_f(v.y);
                v.z = silu_f(v.z); v.w = silu_f(v.w);
            }
            if (out) *(float4*)(out + off) = v;
            if (outb) {
                ushort4 u = make_ushort4(f2b(v.x), f2b(v.y), f2b(v.z), f2b(v.w));
                *(ushort4*)(outb + off) = u;
            }
        }
    }
}

__global__ void combine_rbf(const float* __restrict__ W1, const float* __restrict__ W2,
                            float* __restrict__ C) {
    int l = blockIdx.x;
    const float* w1 = W1 + l * 48;
    const float* w2 = W2 + l * 1024;
    float* c = C + l * 768;
    for (int idx = threadIdx.x; idx < 768; idx += 256) {
        int j = idx >> 7, h = idx & 127;
        float s = 0.f;
#pragma unroll
        for (int p = 0; p < 8; ++p) s += w1[j * 8 + p] * w2[p * 128 + h];
        c[idx] = s;
    }
}

// ------------------------- CSR build -------------------------
__global__ void hist_kernel(const int* __restrict__ idx, int n, int* __restrict__ cnt) {
    int t = blockIdx.x * 256 + threadIdx.x;
    if (t < n) atomicAdd(&cnt[idx[t]], 1);
}

__launch_bounds__(1024)
__global__ void scan1(const int* __restrict__ cnt, int n, int* __restrict__ offs,
                      int* __restrict__ partials) {
    __shared__ int tmp[1024];
    int tid = threadIdx.x;
    int i = blockIdx.x * 1024 + tid;
    int v = (i < n) ? cnt[i] : 0;
    tmp[tid] = v; __syncthreads();
    for (int d = 1; d < 1024; d <<= 1) {
        int t = (tid >= d) ? tmp[tid - d] : 0; __syncthreads();
        tmp[tid] += t; __syncthreads();
    }
    if (i < n) offs[i] = tmp[tid] - v;
    if (tid == 1023) partials[blockIdx.x] = tmp[1023];
}

__launch_bounds__(1024)
__global__ void scan2(int* __restrict__ partials, int nb, int n, int* __restrict__ offs) {
    __shared__ int tmp[1024];
    int tid = threadIdx.x;
    int v = (tid < nb) ? partials[tid] : 0;
    tmp[tid] = v; __syncthreads();
    for (int d = 1; d < 1024; d <<= 1) {
        int t = (tid >= d) ? tmp[tid - d] : 0; __syncthreads();
        tmp[tid] += t; __syncthreads();
    }
    if (tid < nb) partials[tid] = tmp[tid] - v;
    if (tid == 1023) offs[n] = tmp[1023];
}

__launch_bounds__(1024)
__global__ void scan3(int n, int* __restrict__ offs, const int* __restrict__ partials,
                      int* __restrict__ cur) {
    int i = blockIdx.x * 1024 + threadIdx.x;
    if (i < n) { int o = offs[i] + partials[blockIdx.x]; offs[i] = o; cur[i] = o; }
}

__global__ void fill_kernel(const int* __restrict__ idx, int n,
                            int* __restrict__ cur, int* __restrict__ lst) {
    int t = blockIdx.x * 256 + threadIdx.x;
    if (t < n) {
        int p = atomicAdd(&cur[idx[t]], 1);
        lst[p] = t;
    }
}

// ------------------------ triplet stage ------------------------
__launch_bounds__(128)
__global__ void p8_kernel(const float* __restrict__ sbf, const float* __restrict__ W1,
                          float* __restrict__ p8) {
    __shared__ float S[128 * 43];
    __shared__ float Wl[SBF_DIM * 8];
    int tid = threadIdx.x;
    for (int i = tid; i < SBF_DIM * 8; i += 128) Wl[i] = W1[i];
    size_t base = (size_t)blockIdx.x * 128;
    int rows = (TT - base) < 128 ? (int)(TT - base) : 128;
    const float* src = sbf + base * SBF_DIM;
    for (int i = tid; i < rows * SBF_DIM; i += 128) {
        int r = i / SBF_DIM, j = i - r * SBF_DIM;
        S[r * 43 + j] = src[i];
    }
    __syncthreads();
    if (tid >= rows) return;
    float pv[8] = {0.f, 0.f, 0.f, 0.f, 0.f, 0.f, 0.f, 0.f};
    for (int j = 0; j < SBF_DIM; ++j) {
        float sv = S[tid * 43 + j];
#pragma unroll
        for (int p = 0; p < 8; ++p) pv[p] += sv * Wl[j * 8 + p];
    }
    float4* o = (float4*)(p8 + (base + tid) * 8);
    o[0] = make_float4(pv[0], pv[1], pv[2], pv[3]);
    o[1] = make_float4(pv[4], pv[5], pv[6], pv[7]);
}

__launch_bounds__(256)
__global__ void triplet_gather(const float* __restrict__ p8, const float* __restrict__ W2,
                               const unsigned short* __restrict__ xkj,
                               const int* __restrict__ idx_kj,
                               const int* __restrict__ offsT, const int* __restrict__ tlist,
                               unsigned short* __restrict__ agg) {
    int lane = threadIdx.x & 63;
    int wv = threadIdx.x >> 6;
    int e = blockIdx.x * 4 + wv;
    if (e >= EE) return;
    float w2c[8];
#pragma unroll
    for (int p = 0; p < 8; ++p) w2c[p] = W2[p * INTD + lane];
    int b = offsT[e], en = offsT[e + 1];
    float acc = 0.f;
    for (int q = b; q < en; ++q) {
        int t = tlist[q];
        int k = idx_kj[t];
        const float4* pr = (const float4*)(p8 + (size_t)t * 8);
        float4 p0 = pr[0], p1 = pr[1];
        float s = p0.x * w2c[0] + p0.y * w2c[1] + p0.z * w2c[2] + p0.w * w2c[3]
                + p1.x * w2c[4] + p1.y * w2c[5] + p1.z * w2c[6] + p1.w * w2c[7];
        acc += s * b2f(xkj[(size_t)k * INTD + lane]);
    }
    agg[(size_t)e * INTD + lane] = f2b(acc);
}

__launch_bounds__(256)
__global__ void e2_gather(const float* __restrict__ rbf, const float* __restrict__ Wr,
                          const float* __restrict__ e1f, const int* __restrict__ offsE,
                          const int* __restrict__ elist, float* __restrict__ vseg) {
    int h = threadIdx.x & 127;
    int sub = threadIdx.x >> 7;
    int n = blockIdx.x * 2 + sub;
    if (n >= NN) return;
    float c0 = Wr[0 * 128 + h], c1 = Wr[1 * 128 + h], c2 = Wr[2 * 128 + h],
          c3 = Wr[3 * 128 + h], c4 = Wr[4 * 128 + h], c5 = Wr[5 * 128 + h];
    int b = offsE[n], en = offsE[n + 1];
    float a0 = 0.f, a1 = 0.f, a2 = 0.f, a3 = 0.f;
    int q = b;
    for (; q + 4 <= en; q += 4) {
        int ea = elist[q], eb = elist[q + 1], ec = elist[q + 2], ed = elist[q + 3];
        const float* ra = rbf + (size_t)ea * NRAD;
        const float* rb = rbf + (size_t)eb * NRAD;
        const float* rc = rbf + (size_t)ec * NRAD;
        const float* rd = rbf + (size_t)ed * NRAD;
        float fa = e1f[(size_t)ea * 128 + h];
        float fb = e1f[(size_t)eb * 128 + h];
        float fc = e1f[(size_t)ec * 128 + h];
        float fd = e1f[(size_t)ed * 128 + h];
        float sa = ra[0] * c0 + ra[1] * c1 + ra[2] * c2 + ra[3] * c3 + ra[4] * c4 + ra[5] * c5;
        float sb = rb[0] * c0 + rb[1] * c1 + rb[2] * c2 + rb[3] * c3 + rb[4] * c4 + rb[5] * c5;
        float sc = rc[0] * c0 + rc[1] * c1 + rc[2] * c2 + rc[3] * c3 + rc[4] * c4 + rc[5] * c5;
        float sd = rd[0] * c0 + rd[1] * c1 + rd[2] * c2 + rd[3] * c3 + rd[4] * c4 + rd[5] * c5;
        a0 += sa * fa; a1 += sb * fb; a2 += sc * fc; a3 += sd * fd;
    }
    for (; q < en; ++q) {
        int e = elist[q];
        const float* rr = rbf + (size_t)e * NRAD;
        float s = rr[0] * c0 + rr[1] * c1 + rr[2] * c2 + rr[3] * c3 + rr[4] * c4 + rr[5] * c5;
        a0 += s * e1f[(size_t)e * 128 + h];
    }
    vseg[(size_t)n * 128 + h] = (a0 + a1) + (a2 + a3);
}

__global__ void scatter_u0(const float* __restrict__ v, const int* __restrict__ batch,
                           float* __restrict__ u0) {
    int idx = blockIdx.x * 256 + threadIdx.x;
    int h = idx & 127;
    int n = idx >> 7;
    atomicAdd(&u0[(size_t)batch[n] * 128 + h], v[idx]);
}

__launch_bounds__(256)
__global__ void vout_scatter(const float* __restrict__ vn, const float* __restrict__ Wv_out,
                             const int* __restrict__ batch, float* __restrict__ sbatch) {
    int wave = threadIdx.x >> 6, lane = threadIdx.x & 63;
    int n = blockIdx.x * 4 + wave;
    if (n >= NN) return;
    const float* row = vn + (size_t)n * OUT_EMB;
    float s = 0.f;
#pragma unroll
    for (int k = lane; k < OUT_EMB; k += 64) s += row[k] * Wv_out[k];
#pragma unroll
    for (int off = 32; off > 0; off >>= 1) s += __shfl_down(s, off);
    if (lane == 0) atomicAdd(&sbatch[batch[n]], s);
}

__global__ void final_out(const float* __restrict__ u0, const float* __restrict__ sb,
                          float* __restrict__ out) {
    int idx = blockIdx.x * 256 + threadIdx.x;
    out[idx] = u0[idx] + sb[idx >> 7];
}

extern "C" void kernel_launch(void* const* d_in, const int* in_sizes, int n_in,
                              void* d_out, int out_size, void* d_ws, size_t ws_size,
                              hipStream_t stream) {
    const float* x         = (const float*)d_in[0];
    const float* edge_attr = (const float*)d_in[1];
    const float* rbf       = (const float*)d_in[2];
    const float* sbf       = (const float*)d_in[3];
    const int*   iidx      = (const int*)d_in[4];
    const int*   idx_kj    = (const int*)d_in[5];
    const int*   idx_ji    = (const int*)d_in[6];
    const int*   batch     = (const int*)d_in[7];
    const float* W_node    = (const float*)d_in[8];
    const float* W_edge    = (const float*)d_in[9];
    const float* We_rbf1   = (const float*)d_in[10];
    const float* We_rbf2   = (const float*)d_in[11];
    const float* We_sbf1   = (const float*)d_in[12];
    const float* We_sbf2   = (const float*)d_in[13];
    const float* We_rbf    = (const float*)d_in[14];
    const float* We_kj     = (const float*)d_in[15];
    const float* be_kj     = (const float*)d_in[16];
    const float* We_ji     = (const float*)d_in[17];
    const float* be_ji     = (const float*)d_in[18];
    const float* We_down   = (const float*)d_in[19];
    const float* We_up     = (const float*)d_in[20];
    const float* We_cat    = (const float*)d_in[21];
    const float* Wres_b    = (const float*)d_in[22];
    const float* bres_b    = (const float*)d_in[23];
    const float* We_lin    = (const float*)d_in[24];
    const float* be_lin    = (const float*)d_in[25];
    const float* Wres_a    = (const float*)d_in[26];
    const float* bres_a    = (const float*)d_in[27];
    const float* Wv_up     = (const float*)d_in[28];
    const float* bv_up     = (const float*)d_in[29];
    const float* Wv_lins   = (const float*)d_in[30];
    const float* bv_lins   = (const float*)d_in[31];
    const float* Wv_out    = (const float*)d_in[32];
    float* out = (float*)d_out;

    // ---- workspace layout ----
    unsigned short* e1b  = (unsigned short*)d_ws;            // E*128 bf16
    unsigned short* buf1 = e1b  + (size_t)EE * HH;           // E*128 bf16 (x_ji)
    unsigned short* scr2 = buf1 + (size_t)EE * HH;           // E*128 slot (p8 alias)
    unsigned short* bufC = scr2 + (size_t)EE * HH;           // E*64 bf16 (xkj_down)
    unsigned short* bufD = bufC + (size_t)EE * INTD;         // E*64 bf16 (agg)
    unsigned short* endu = bufD + (size_t)EE * INTD;
    float* e1f    = (float*)endu;                            // E*128 fp32 master
    float* tail   = e1f + (size_t)EE * HH;
    float* u0     = tail;                                    // B*128
    float* sbatch = u0 + BB * HH;                            // 256
    float* Crbf   = sbatch + 256;                            // 4*768
    int*   iptr   = (int*)(Crbf + 4 * 768);
    int* cntT  = iptr;               iptr += EE;
    int* offsT = iptr;               iptr += EE + 1;
    int* curT  = iptr;               iptr += EE;
    int* tlist = iptr;               iptr += TT;
    int* cntE  = iptr;               iptr += NN;
    int* offsE = iptr;               iptr += NN + 1;
    int* curE  = iptr;               iptr += NN;
    int* elist = iptr;               iptr += EE;
    int* partials = iptr;            iptr += 1024;
    unsigned short* wptr = (unsigned short*)iptr;
    unsigned short* wt_ji   = wptr;  wptr += 4 * 16384;
    unsigned short* wt_kj   = wptr;  wptr += 4 * 16384;
    unsigned short* wt_down = wptr;  wptr += 4 * 8192;
    unsigned short* wt_up   = wptr;  wptr += 4 * 8192;
    unsigned short* wt_cat  = wptr;  wptr += 4 * 16384;
    unsigned short* wt_resb = wptr;  wptr += 8 * 16384;
    unsigned short* wt_lin  = wptr;  wptr += 4 * 16384;
    unsigned short* wt_resa = wptr;  wptr += 16 * 16384;
    float* p8 = (float*)scr2;                                // [T,8] fp32
    float* vseg = (float*)bufC;                              // N*128 fp32 (post-MK2)
    float* vn1  = vseg + (size_t)NN * HH;                    // N*256
    float* vn2  = vn1 + (size_t)NN * OUT_EMB;                // N*256

    hipMemsetAsync(u0, 0, (size_t)BB * HH * sizeof(float), stream);
    hipMemsetAsync(sbatch, 0, 256 * sizeof(float), stream);
    combine_rbf<<<4, 256, 0, stream>>>(We_rbf1, We_rbf2, Crbf);

    transpose_w<<<(4 * 16384 + 255) / 256, 256, 0, stream>>>(We_ji, wt_ji, 4, 128, 128);
    transpose_w<<<(4 * 16384 + 255) / 256, 256, 0, stream>>>(We_kj, wt_kj, 4, 128, 128);
    transpose_w<<<(4 * 8192 + 255) / 256, 256, 0, stream>>>(We_down, wt_down, 4, 128, 64);
    transpose_w<<<(4 * 8192 + 255) / 256, 256, 0, stream>>>(We_up, wt_up, 4, 64, 128);
    transpose_w<<<(4 * 16384 + 255) / 256, 256, 0, stream>>>(We_cat, wt_cat, 4, 128, 128);
    transpose_w<<<(8 * 16384 + 255) / 256, 256, 0, stream>>>(Wres_b, wt_resb, 8, 128, 128);
    transpose_w<<<(4 * 16384 + 255) / 256, 256, 0, stream>>>(We_lin, wt_lin, 4, 128, 128);
    transpose_w<<<(16 * 16384 + 255) / 256, 256, 0, stream>>>(Wres_a, wt_resa, 16, 128, 128);

    hipMemsetAsync(cntT, 0, EE * sizeof(int), stream);
    hipMemsetAsync(cntE, 0, NN * sizeof(int), stream);
    hist_kernel<<<(TT + 255) / 256, 256, 0, stream>>>(idx_ji, TT, cntT);
    hist_kernel<<<(EE + 255) / 256, 256, 0, stream>>>(iidx, EE, cntE);
    int nbT = (EE + 1023) / 1024, nbE = (NN + 1023) / 1024;
    scan1<<<nbT, 1024, 0, stream>>>(cntT, EE, offsT, partials);
    scan2<<<1, 1024, 0, stream>>>(partials, nbT, EE, offsT);
    scan3<<<nbT, 1024, 0, stream>>>(EE, offsT, partials, curT);
    fill_kernel<<<(TT + 255) / 256, 256, 0, stream>>>(idx_ji, TT, curT, tlist);
    scan1<<<nbE, 1024, 0, stream>>>(cntE, NN, offsE, partials);
    scan2<<<1, 1024, 0, stream>>>(partials, nbE, NN, offsE);
    scan3<<<nbE, 1024, 0, stream>>>(NN, offsE, partials, curE);
    fill_kernel<<<(EE + 255) / 256, 256, 0, stream>>>(iidx, EE, curE, elist);

    gemm_k<12><<<EE / 32, 256, 0, stream>>>(edge_attr, W_edge, nullptr, e1f, e1b, HH, 0);
    gemm_k<48><<<NN / 32, 256, 0, stream>>>(x, W_node, nullptr, vseg, nullptr, HH, 0);
    scatter_u0<<<NN * HH / 256, 256, 0, stream>>>(vseg, batch, u0);

    const int GR = EE / 128;  // 3125
    for (int l = 0; l < 4; ++l) {
        mk1<<<GR, 512, 0, stream>>>(e1b, wt_ji + l * 16384, wt_kj + l * 16384,
                                    wt_down + l * 8192, be_ji + l * HH, be_kj + l * HH,
                                    rbf, Crbf + l * 768, buf1, bufC);
        p8_kernel<<<(TT + 127) / 128, 128, 0, stream>>>(sbf, We_sbf1 + l * SBF_DIM * 8, p8);
        triplet_gather<<<EE / 4, 256, 0, stream>>>(p8, We_sbf2 + l * 8 * INTD, bufC,
                                                   idx_kj, offsT, tlist, bufD);
        mk2<<<GR, 512, 0, stream>>>(bufD, buf1, e1f, e1b,
            wt_up + l * 8192, wt_cat + l * 16384,
            wt_resb + (l * 2 + 0) * 16384, wt_resb + (l * 2 + 1) * 16384,
            wt_lin + l * 16384,
            wt_resa + ((l * 2 + 0) * 2 + 0) * 16384, wt_resa + ((l * 2 + 0) * 2 + 1) * 16384,
            wt_resa + ((l * 2 + 1) * 2 + 0) * 16384, wt_resa + ((l * 2 + 1) * 2 + 1) * 16384,
            bres_b + (l * 2 + 0) * HH, bres_b + (l * 2 + 1) * HH, be_lin + l * HH,
            bres_a + ((l * 2 + 0) * 2 + 0) * HH, bres_a + ((l * 2 + 0) * 2 + 1) * HH,
            bres_a + ((l * 2 + 1) * 2 + 0) * HH, bres_a + ((l * 2 + 1) * 2 + 1) * HH);
        e2_gather<<<(NN + 1) / 2, 256, 0, stream>>>(rbf, We_rbf + (size_t)l * NRAD * HH,
                                                    e1f, offsE, elist, vseg);
        gemm_k<128><<<NN / 32, 256, 0, stream>>>(vseg, Wv_up + (size_t)l * HH * OUT_EMB,
                                                 bv_up + l * OUT_EMB, vn1, nullptr, OUT_EMB, 0);
        gemm_k<256><<<NN / 32, 256, 0, stream>>>(vn1, Wv_lins + (size_t)(l * 3 + 0) * 65536,
                                                 bv_lins + (l * 3 + 0) * 256, vn2, nullptr, OUT_EMB, 1);
        gemm_k<256><<<NN / 32, 256, 0, stream>>>(vn2, Wv_lins + (size_t)(l * 3 + 1) * 65536,
                                                 bv_lins + (l * 3 + 1) * 256, vn1, nullptr, OUT_EMB, 1);
        gemm_k<256><<<NN / 32, 256, 0, stream>>>(vn1, Wv_lins + (size_t)(l * 3 + 2) * 65536,
                                                 bv_lins + (l * 3 + 2) * 256, vn2, nullptr, OUT_EMB, 1);
        vout_scatter<<<NN / 4, 256, 0, stream>>>(vn2, Wv_out + l * OUT_EMB, batch, sbatch);
    }
    final_out<<<BB * HH / 256, 256, 0, stream>>>(u0, sbatch, out);
}

// Round 5
// 5986.220 us; speedup vs baseline: 1.3664x; 1.1534x over previous
//
#include <hip/hip_runtime.h>
#include <hip/hip_bf16.h>
#include <cstddef>

#define NN 20000
#define EE 400000
#define TT 1500000
#define BB 128
#define HH 128
#define INTD 64
#define OUT_EMB 256
#define SBF_DIM 42
#define NRAD 6

#define SA_C 136   // LDS row stride (ushorts): 272B, 16B-aligned, 2-way bank (free)

typedef __attribute__((ext_vector_type(8))) short bf16x8;
typedef __attribute__((ext_vector_type(4))) float f32x4;

__device__ __forceinline__ float silu_f(float v) {
    return v / (1.0f + __expf(-v));
}
__device__ __forceinline__ unsigned short f2b(float f) {
    __hip_bfloat16 h = __float2bfloat16(f);
    unsigned short u; __builtin_memcpy(&u, &h, 2); return u;
}
__device__ __forceinline__ float b2f(unsigned short u) {
    __hip_bfloat16 h; __builtin_memcpy(&h, &u, 2); return __bfloat162float(h);
}

// --- async weight staging: global->reg (issue early), reg->LDS (after barrier) ---
// W is row-major [rows][K] contiguous; linear load. 512 threads.
template <int NU4>
__device__ __forceinline__ void loadWlin(uint4 (&rg)[NU4], const unsigned short* W, int tid) {
#pragma unroll
    for (int j = 0; j < NU4; ++j) rg[j] = *(const uint4*)(W + ((size_t)tid + j * 512) * 8);
}
// SEGS = uint4 per row (16 for K=128, 8 for K=64)
template <int NU4, int SEGS>
__device__ __forceinline__ void storeWs(const uint4 (&rg)[NU4], unsigned short* Ws, int tid) {
#pragma unroll
    for (int j = 0; j < NU4; ++j) {
        int i = tid + j * 512;
        int n = i / SEGS, seg = i % SEGS;
        *(uint4*)&Ws[n * SA_C + seg * 8] = rg[j];
    }
}

// packed epilogue store: 4 consecutive features of one edge row -> ds_write_b64
__device__ __forceinline__ void st4(unsigned short* Cs, int m, int f0, const float* v) {
    ushort4 u = make_ushort4(f2b(v[0]), f2b(v[1]), f2b(v[2]), f2b(v[3]));
    *(ushort4*)&Cs[m * SA_C + f0] = u;
}

// Operand-swapped wave tile 32(feat) x 64(edge): A = W^T rows (from Ws),
// B = X rows (edges, from Cs). Output: row = feature (quad*4+r), col = edge (lm).
template <int KCNT>
__device__ __forceinline__ void mfma_f(const unsigned short* Cs, const unsigned short* Ws,
                                       int lm, int quad, int fw0, int ew0, f32x4 acc[2][4]) {
#pragma unroll
    for (int kc = 0; kc < KCNT; ++kc) {
        bf16x8 wf[2], xf[4];
#pragma unroll
        for (int mi = 0; mi < 2; ++mi)
            wf[mi] = *(const bf16x8*)&Ws[(fw0 + mi * 16 + lm) * SA_C + kc * 32 + quad * 8];
#pragma unroll
        for (int ni = 0; ni < 4; ++ni)
            xf[ni] = *(const bf16x8*)&Cs[(ew0 + ni * 16 + lm) * SA_C + kc * 32 + quad * 8];
#pragma unroll
        for (int mi = 0; mi < 2; ++mi)
#pragma unroll
            for (int ni = 0; ni < 4; ++ni)
                acc[mi][ni] = __builtin_amdgcn_mfma_f32_16x16x32_bf16(wf[mi], xf[ni], acc[mi][ni], 0, 0, 0);
    }
}

// down GEMM wave tile 32(dfeat) x 32(edge)
template <int KCNT>
__device__ __forceinline__ void mfma_d2(const unsigned short* Cs, const unsigned short* Ws,
                                        int lm, int quad, int fw0, int ew0, f32x4 acc[2][2]) {
#pragma unroll
    for (int kc = 0; kc < KCNT; ++kc) {
        bf16x8 wf[2], xf[2];
#pragma unroll
        for (int mi = 0; mi < 2; ++mi)
            wf[mi] = *(const bf16x8*)&Ws[(fw0 + mi * 16 + lm) * SA_C + kc * 32 + quad * 8];
#pragma unroll
        for (int ni = 0; ni < 2; ++ni)
            xf[ni] = *(const bf16x8*)&Cs[(ew0 + ni * 16 + lm) * SA_C + kc * 32 + quad * 8];
#pragma unroll
        for (int mi = 0; mi < 2; ++mi)
#pragma unroll
            for (int ni = 0; ni < 2; ++ni)
                acc[mi][ni] = __builtin_amdgcn_mfma_f32_16x16x32_bf16(wf[mi], xf[ni], acc[mi][ni], 0, 0, 0);
    }
}

// ---------------------------------------------------------------------------
// MK1 (512 threads, 8 waves): x_ji = silu(e1@Wji+bji) -> buf1 ;
//   x_kj = silu(e1@Wkj+bkj)*r ; bufC = silu(x_kjr @ Wdown)
// ---------------------------------------------------------------------------
__global__ __launch_bounds__(512, 2)
void mk1(const unsigned short* __restrict__ e1b,
         const unsigned short* __restrict__ w_ji, const unsigned short* __restrict__ w_kj,
         const unsigned short* __restrict__ w_down,
         const float* __restrict__ be_ji, const float* __restrict__ be_kj,
         const float* __restrict__ rbf, const float* __restrict__ Crbf_l,
         unsigned short* __restrict__ buf1, unsigned short* __restrict__ bufC) {
    __shared__ unsigned short Cs[128 * SA_C];
    __shared__ unsigned short Ws[128 * SA_C];
    __shared__ float rbfS[128 * 6];
    __shared__ float CrbfS[768];

    const int tid = threadIdx.x;
    const size_t row0 = (size_t)blockIdx.x * 128;
    const int lane = tid & 63, wave = tid >> 6, lm = lane & 15, quad = lane >> 4;
    const int rw0 = (wave >> 1) * 32;   // feature base (4 groups)
    const int cw0 = (wave & 1) * 64;    // edge base (2 groups)
    const int fw0d = (wave & 1) * 32;   // down: feature base (2 groups)
    const int ew0d = (wave >> 1) * 32;  // down: edge base (4 groups)

    uint4 wreg[4]; uint4 wregd[2];

    // initial staging: Cs <- e1b tile (full K=128), Ws <- Wji full, rbf+Crbf tiles
    for (int i = tid; i < 2048; i += 512) {
        int r = i >> 4, seg = i & 15;
        *(uint4*)&Cs[r * SA_C + seg * 8] = *(const uint4*)(e1b + (row0 + r) * 128 + seg * 8);
    }
    loadWlin<4>(wreg, w_ji, tid); storeWs<4, 16>(wreg, Ws, tid);
    for (int i = tid; i < 768; i += 512) { rbfS[i] = rbf[row0 * 6 + i]; CrbfS[i] = Crbf_l[i]; }
    __syncthreads();

    // ---- ji GEMM -> jreg (kept in registers) ----
    f32x4 jreg[2][4], acc[2][4];
#pragma unroll
    for (int mi = 0; mi < 2; ++mi)
#pragma unroll
        for (int ni = 0; ni < 4; ++ni) jreg[mi][ni] = (f32x4){0.f, 0.f, 0.f, 0.f};
    loadWlin<4>(wreg, w_kj, tid);
    mfma_f<4>(Cs, Ws, lm, quad, rw0, cw0, jreg);
    __syncthreads();
    storeWs<4, 16>(wreg, Ws, tid);
    __syncthreads();

    // ---- kj GEMM ----
#pragma unroll
    for (int mi = 0; mi < 2; ++mi)
#pragma unroll
        for (int ni = 0; ni < 4; ++ni) acc[mi][ni] = (f32x4){0.f, 0.f, 0.f, 0.f};
    loadWlin<2>(wregd, w_down, tid);   // Wdown [64][128] -> 1024 uint4
    mfma_f<4>(Cs, Ws, lm, quad, rw0, cw0, acc);
    __syncthreads();
    // epi kj: silu + bias, r-scale; packed writes overwrite Cs; stage Wdown
#pragma unroll
    for (int mi = 0; mi < 2; ++mi) {
        const int f0 = rw0 + mi * 16 + quad * 4;
        const float4 bb = *(const float4*)(be_kj + f0);
#pragma unroll
        for (int ni = 0; ni < 4; ++ni) {
            const int m = cw0 + ni * 16 + lm;
            float4 rv = {0.f, 0.f, 0.f, 0.f};
#pragma unroll
            for (int j = 0; j < 6; ++j) {
                float rb = rbfS[m * 6 + j];
                float4 c4 = *(const float4*)&CrbfS[j * 128 + f0];
                rv.x += rb * c4.x; rv.y += rb * c4.y; rv.z += rb * c4.z; rv.w += rb * c4.w;
            }
            float v4[4];
#pragma unroll
            for (int r = 0; r < 4; ++r) {
                float v = silu_f(acc[mi][ni][r] + (&bb.x)[r]);
                v4[r] = b2f(f2b(v)) * (&rv.x)[r];
            }
            st4(Cs, m, f0, v4);
        }
    }
    storeWs<2, 16>(wregd, Ws, tid);
    __syncthreads();

    // ---- down GEMM (output 64 dfeat x 128 edges) ----
    f32x4 accd[2][2];
#pragma unroll
    for (int mi = 0; mi < 2; ++mi)
#pragma unroll
        for (int ni = 0; ni < 2; ++ni) accd[mi][ni] = (f32x4){0.f, 0.f, 0.f, 0.f};
    mfma_d2<4>(Cs, Ws, lm, quad, fw0d, ew0d, accd);
    __syncthreads();
    // epi down -> Cs cols 0..63, packed
#pragma unroll
    for (int mi = 0; mi < 2; ++mi) {
        const int f0 = fw0d + mi * 16 + quad * 4;
#pragma unroll
        for (int ni = 0; ni < 2; ++ni) {
            const int m = ew0d + ni * 16 + lm;
            float v4[4];
#pragma unroll
            for (int r = 0; r < 4; ++r) v4[r] = silu_f(accd[mi][ni][r]);
            st4(Cs, m, f0, v4);
        }
    }
    __syncthreads();
    // coalesced copy Cs(128x64) -> bufC
    for (int i = tid; i < 1024; i += 512) {
        int r = i >> 3, seg = i & 7;
        *(uint4*)(bufC + (row0 + r) * 64 + seg * 8) = *(const uint4*)&Cs[r * SA_C + seg * 8];
    }
    __syncthreads();
    // epi ji -> Cs (packed), then coalesced copy -> buf1
#pragma unroll
    for (int mi = 0; mi < 2; ++mi) {
        const int f0 = rw0 + mi * 16 + quad * 4;
        const float4 bj = *(const float4*)(be_ji + f0);
#pragma unroll
        for (int ni = 0; ni < 4; ++ni) {
            const int m = cw0 + ni * 16 + lm;
            float v4[4];
#pragma unroll
            for (int r = 0; r < 4; ++r) v4[r] = silu_f(jreg[mi][ni][r] + (&bj.x)[r]);
            st4(Cs, m, f0, v4);
        }
    }
    __syncthreads();
    for (int i = tid; i < 2048; i += 512) {
        int r = i >> 4, seg = i & 15;
        *(uint4*)(buf1 + (row0 + r) * 128 + seg * 8) = *(const uint4*)&Cs[r * SA_C + seg * 8];
    }
}

// ---------------------------------------------------------------------------
// MK2 (512 threads, 8 waves): up -> (+x_ji) cat -> rb0a -> rb0b(+state) ->
//   lin(+e1f_old, state=) -> ra0a -> ra0b -> ra1a -> ra1b -> write e1f, e1b
// Full-K weight buffer: 2 barriers per GEMM phase.
// Final writeback staged through fp32 LDS overlay (full-line e1f/e1b stores).
// ---------------------------------------------------------------------------
__global__ __launch_bounds__(512, 2)
void mk2(const unsigned short* __restrict__ bufD, const unsigned short* __restrict__ buf1g,
         float* __restrict__ e1f, unsigned short* __restrict__ e1b,
         const unsigned short* __restrict__ w_up, const unsigned short* __restrict__ w_cat,
         const unsigned short* __restrict__ w_rb0, const unsigned short* __restrict__ w_rb1,
         const unsigned short* __restrict__ w_lin,
         const unsigned short* __restrict__ w_ra0, const unsigned short* __restrict__ w_ra1,
         const unsigned short* __restrict__ w_ra2, const unsigned short* __restrict__ w_ra3,
         const float* __restrict__ b_rb0, const float* __restrict__ b_rb1,
         const float* __restrict__ b_lin,
         const float* __restrict__ b_ra0, const float* __restrict__ b_ra1,
         const float* __restrict__ b_ra2, const float* __restrict__ b_ra3) {
    __shared__ unsigned short SMEM[2 * 128 * SA_C];
    unsigned short* Cs = SMEM;
    unsigned short* Ws = SMEM + 128 * SA_C;
    float* Fs = (float*)SMEM;              // final overlay: [128][132] fp32 (67584B < 69632B)

    const int tid = threadIdx.x;
    const size_t row0 = (size_t)blockIdx.x * 128;
    const int lane = tid & 63, wave = tid >> 6, lm = lane & 15, quad = lane >> 4;
    const int rw0 = (wave >> 1) * 32, cw0 = (wave & 1) * 64;

    f32x4 acc[2][4], state[2][4];
    uint4 wreg[4];

#define ZERO_ACC()                                                 \
    _Pragma("unroll") for (int mi = 0; mi < 2; ++mi)               \
    _Pragma("unroll") for (int ni = 0; ni < 4; ++ni)               \
        acc[mi][ni] = (f32x4){0.f, 0.f, 0.f, 0.f};

#define TILE_LOOP(PRELOAD, BODY)                                \
    _Pragma("unroll") for (int mi = 0; mi < 2; ++mi) {          \
      const int f0 = rw0 + mi * 16 + quad * 4;                  \
      _Pragma("unroll") for (int ni = 0; ni < 4; ++ni) {        \
        const int m = cw0 + ni * 16 + lm;                       \
        const size_t goff = (size_t)(row0 + m) * 128 + f0;      \
        (void)goff;                                             \
        PRELOAD                                                 \
        float v4[4];                                            \
        _Pragma("unroll") for (int r = 0; r < 4; ++r) { BODY }  \
        st4(Cs, m, f0, v4); } }

    // initial staging: Cs <- bufD tile (K=64), Ws <- Wup [128][64]
    for (int i = tid; i < 1024; i += 512) {
        int r = i >> 3, seg = i & 7;
        *(uint4*)&Cs[r * SA_C + seg * 8] = *(const uint4*)(bufD + (row0 + r) * 64 + seg * 8);
    }
    {
        uint4 wu[2];
        loadWlin<2>(wu, w_up, tid); storeWs<2, 8>(wu, Ws, tid);
    }
    __syncthreads();

    // ---- up (K=64, no bias): Cs = bf16(x_ji + bf16(silu(acc))) ----
    ZERO_ACC()
    loadWlin<4>(wreg, w_cat, tid);
    mfma_f<2>(Cs, Ws, lm, quad, rw0, cw0, acc);
    __syncthreads();
    TILE_LOOP(
        ushort4 xj = *(const ushort4*)(buf1g + goff);,
        { float v = silu_f(acc[mi][ni][r]);
          v4[r] = b2f((&xj.x)[r]) + b2f(f2b(v)); }
    )
    storeWs<4, 16>(wreg, Ws, tid);
    __syncthreads();

    // full-K phase: mfma -> sync -> epilogue + stage next W -> sync
#define PHASE_HEAD(WNEXT)                          \
    ZERO_ACC()                                     \
    loadWlin<4>(wreg, (WNEXT), tid);               \
    mfma_f<4>(Cs, Ws, lm, quad, rw0, cw0, acc);    \
    __syncthreads();

#define PHASE_TAIL()                               \
    storeWs<4, 16>(wreg, Ws, tid);                 \
    __syncthreads();

    // ---- cat (no bias): state = silu(acc) ----
    PHASE_HEAD(w_rb0)
    TILE_LOOP(,
        { float v = silu_f(acc[mi][ni][r]); state[mi][ni][r] = v; v4[r] = v; }
    )
    PHASE_TAIL()

    // ---- rb0a ----
    PHASE_HEAD(w_rb1)
    TILE_LOOP(
        float4 b4 = *(const float4*)(b_rb0 + f0);,
        { v4[r] = silu_f(acc[mi][ni][r] + (&b4.x)[r]); }
    )
    PHASE_TAIL()

    // ---- rb0b: state += silu ----
    PHASE_HEAD(w_lin)
    TILE_LOOP(
        float4 b4 = *(const float4*)(b_rb1 + f0);,
        { float v = state[mi][ni][r] + silu_f(acc[mi][ni][r] + (&b4.x)[r]);
          state[mi][ni][r] = v; v4[r] = v; }
    )
    PHASE_TAIL()

    // ---- lin: state = silu(acc+b) + e1f_old ----
    PHASE_HEAD(w_ra0)
    TILE_LOOP(
        float4 b4 = *(const float4*)(b_lin + f0);
        float4 e4 = *(const float4*)(e1f + goff);,
        { float v = silu_f(acc[mi][ni][r] + (&b4.x)[r]) + (&e4.x)[r];
          state[mi][ni][r] = v; v4[r] = v; }
    )
    PHASE_TAIL()

    // ---- ra0a ----
    PHASE_HEAD(w_ra1)
    TILE_LOOP(
        float4 b4 = *(const float4*)(b_ra0 + f0);,
        { v4[r] = silu_f(acc[mi][ni][r] + (&b4.x)[r]); }
    )
    PHASE_TAIL()

    // ---- ra0b: state += silu ----
    PHASE_HEAD(w_ra2)
    TILE_LOOP(
        float4 b4 = *(const float4*)(b_ra1 + f0);,
        { float v = state[mi][ni][r] + silu_f(acc[mi][ni][r] + (&b4.x)[r]);
          state[mi][ni][r] = v; v4[r] = v; }
    )
    PHASE_TAIL()

    // ---- ra1a ----
    PHASE_HEAD(w_ra3)
    TILE_LOOP(
        float4 b4 = *(const float4*)(b_ra2 + f0);,
        { v4[r] = silu_f(acc[mi][ni][r] + (&b4.x)[r]); }
    )
    PHASE_TAIL()

    // ---- ra1b (final): state += silu; stage fp32 tile -> Fs overlay ----
    ZERO_ACC()
    mfma_f<4>(Cs, Ws, lm, quad, rw0, cw0, acc);
    __syncthreads();   // all Cs/Ws reads done; SMEM free for Fs overlay
#pragma unroll
    for (int mi = 0; mi < 2; ++mi) {
        const int f0 = rw0 + mi * 16 + quad * 4;
        const float4 b4 = *(const float4*)(b_ra3 + f0);
#pragma unroll
        for (int ni = 0; ni < 4; ++ni) {
            const int m = cw0 + ni * 16 + lm;
            float4 ev;
#pragma unroll
            for (int r = 0; r < 4; ++r)
                (&ev.x)[r] = state[mi][ni][r] + silu_f(acc[mi][ni][r] + (&b4.x)[r]);
            *(float4*)&Fs[m * 132 + f0] = ev;
        }
    }
    __syncthreads();
    // coalesced full-row writeback: e1f fp32 + e1b bf16
    for (int i = tid; i < 4096; i += 512) {
        int r = i >> 5, s4 = (i & 31) * 4;
        *(float4*)(e1f + (row0 + r) * 128 + s4) = *(const float4*)&Fs[r * 132 + s4];
    }
    for (int i = tid; i < 2048; i += 512) {
        int r = i >> 4, s8 = (i & 15) * 8;
        const float* fr = Fs + r * 132 + s8;
        float4 a = *(const float4*)fr, b = *(const float4*)(fr + 4);
        *(ushort4*)(e1b + (row0 + r) * 128 + s8) =
            make_ushort4(f2b(a.x), f2b(a.y), f2b(a.z), f2b(a.w));
        *(ushort4*)(e1b + (row0 + r) * 128 + s8 + 4) =
            make_ushort4(f2b(b.x), f2b(b.y), f2b(b.z), f2b(b.w));
    }
#undef PHASE_HEAD
#undef PHASE_TAIL
#undef TILE_LOOP
#undef ZERO_ACC
}

// ---------------------------------------------------------------------------
// MKV (512 threads, 8 waves, 137KB LDS, 1 block/CU): fused node pipeline
//   vn = vseg@Wvup + b ; 3x vn = silu(vn@W+b) ; s = vn@Wv_out ; scatter batch
// One block per 128 nodes. Weights bf16 [out][in] (pre-transposed).
// ---------------------------------------------------------------------------
__device__ __forceinline__ void loadW8v(uint4 (&rg)[8], const unsigned short* W,
                                        int rowstride, int co, int tid) {
#pragma unroll
    for (int j = 0; j < 8; ++j) {
        int i = tid + j * 512;
        int n = i >> 4, seg = i & 15;
        rg[j] = *(const uint4*)(W + (size_t)n * rowstride + co + seg * 8);
    }
}
__device__ __forceinline__ void storeW8v(const uint4 (&rg)[8], unsigned short* Ws, int tid) {
#pragma unroll
    for (int j = 0; j < 8; ++j) {
        int i = tid + j * 512;
        int n = i >> 4, seg = i & 15;
        *(uint4*)&Ws[n * 136 + seg * 8] = rg[j];
    }
}

template <int KCNT>
__device__ __forceinline__ void mfma_v(const unsigned short* Cs, int c0,
                                       const unsigned short* Ws, int lm, int quad,
                                       int fw0, f32x4 acc[2][8]) {
#pragma unroll
    for (int kc = 0; kc < KCNT; ++kc) {
        bf16x8 wf[2];
#pragma unroll
        for (int mi = 0; mi < 2; ++mi)
            wf[mi] = *(const bf16x8*)&Ws[(fw0 + mi * 16 + lm) * 136 + kc * 32 + quad * 8];
#pragma unroll
        for (int ni = 0; ni < 8; ++ni) {
            bf16x8 xf = *(const bf16x8*)&Cs[(ni * 16 + lm) * 264 + c0 + kc * 32 + quad * 8];
#pragma unroll
            for (int mi = 0; mi < 2; ++mi)
                acc[mi][ni] = __builtin_amdgcn_mfma_f32_16x16x32_bf16(wf[mi], xf, acc[mi][ni], 0, 0, 0);
        }
    }
}

__global__ __launch_bounds__(512, 1)
void mkv(const float* __restrict__ vseg, const unsigned short* __restrict__ wtu,
         const unsigned short* __restrict__ wtl, const float* __restrict__ bu,
         const float* __restrict__ bls, const float* __restrict__ wvout,
         const int* __restrict__ batch, float* __restrict__ sbatch) {
    __shared__ unsigned short SM[128 * 264 + 256 * 136];  // 67584B + 69632B = 137216B
    unsigned short* Cs = SM;                 // [128 nodes][264] (256 feat + pad)
    unsigned short* Ws = SM + 128 * 264;     // [256 out][136] (128 K + pad)

    const int tid = threadIdx.x;
    const size_t row0 = (size_t)blockIdx.x * 128;
    const int lane = tid & 63, wave = tid >> 6, lm = lane & 15, quad = lane >> 4;
    const int fw0 = wave * 32;

    f32x4 acc[2][8];
    uint4 wreg[8];

#define ZERO8()                                              \
    _Pragma("unroll") for (int mi = 0; mi < 2; ++mi)         \
    _Pragma("unroll") for (int ni = 0; ni < 8; ++ni)         \
        acc[mi][ni] = (f32x4){0.f, 0.f, 0.f, 0.f};

#define EPI_V(BIAS, ACT)                                              \
    _Pragma("unroll") for (int mi = 0; mi < 2; ++mi) {                \
      const int f0 = fw0 + mi * 16 + quad * 4;                        \
      const float4 b4 = *(const float4*)((BIAS) + f0);                \
      _Pragma("unroll") for (int ni = 0; ni < 8; ++ni) {              \
        const int m = ni * 16 + lm;                                   \
        float v4[4];                                                  \
        _Pragma("unroll") for (int r2 = 0; r2 < 4; ++r2) {            \
            float v = acc[mi][ni][r2] + (&b4.x)[r2];                  \
            if (ACT) v = silu_f(v);                                   \
            v4[r2] = v; }                                             \
        *(ushort4*)&Cs[m * 264 + f0] =                                \
            make_ushort4(f2b(v4[0]), f2b(v4[1]), f2b(v4[2]), f2b(v4[3])); } }

    // stage Cs <- vseg (fp32 -> bf16), Ws <- Wvup^T [256][128]
    for (int i = tid; i < 2048; i += 512) {
        int r = i >> 4, c8 = (i & 15) * 8;
        size_t sr = row0 + r; if (sr > NN - 1) sr = NN - 1;
        const float* src = vseg + sr * 128 + c8;
        float4 a = *(const float4*)src, b = *(const float4*)(src + 4);
        *(ushort4*)&Cs[r * 264 + c8] = make_ushort4(f2b(a.x), f2b(a.y), f2b(a.z), f2b(a.w));
        *(ushort4*)&Cs[r * 264 + c8 + 4] = make_ushort4(f2b(b.x), f2b(b.y), f2b(b.z), f2b(b.w));
    }
    loadW8v(wreg, wtu, 128, 0, tid); storeW8v(wreg, Ws, tid);
    __syncthreads();

    // ---- vup (K=128, no act) ----
    ZERO8()
    loadW8v(wreg, wtl, 256, 0, tid);          // lin0 half0 prefetch
    mfma_v<4>(Cs, 0, Ws, lm, quad, fw0, acc);
    __syncthreads();
    EPI_V(bu, 0)
    storeW8v(wreg, Ws, tid);
    __syncthreads();

    // ---- 3 lins (K=256 in two halves) ----
    const unsigned short* wlp[3] = {wtl, wtl + 65536, wtl + 131072};
#pragma unroll
    for (int k = 0; k < 3; ++k) {
        loadW8v(wreg, wlp[k], 256, 128, tid);   // half1 prefetch
        ZERO8()
        mfma_v<4>(Cs, 0, Ws, lm, quad, fw0, acc);
        __syncthreads();
        storeW8v(wreg, Ws, tid);
        __syncthreads();
        if (k < 2) loadW8v(wreg, wlp[k + 1], 256, 0, tid);  // next half0 prefetch
        mfma_v<4>(Cs, 128, Ws, lm, quad, fw0, acc);
        __syncthreads();
        EPI_V(bls + k * 256, 1)
        if (k < 2) storeW8v(wreg, Ws, tid);
        __syncthreads();
    }

    // ---- vout dot + batch scatter ----
    float* WoS = (float*)Ws;
    if (tid < 64) ((float4*)WoS)[tid] = ((const float4*)wvout)[tid];
    __syncthreads();
    {
        int r = tid >> 2, p = tid & 3;
        float s = 0.f;
        const unsigned short* cr = Cs + r * 264 + p * 64;
        const float* wc = WoS + p * 64;
#pragma unroll
        for (int j = 0; j < 64; ++j) s += b2f(cr[j]) * wc[j];
        s += __shfl_down(s, 1);
        s += __shfl_down(s, 2);
        if (p == 0 && row0 + r < NN) atomicAdd(&sbatch[batch[row0 + r]], s);
    }
#undef ZERO8
#undef EPI_V
}

// weight transpose+bf16: src fp32 [B,K,N] -> dst bf16 [B,N,K]
__global__ void transpose_w(const float* __restrict__ src, unsigned short* __restrict__ dst,
                            int B, int K, int N) {
    size_t total = (size_t)B * K * N;
    size_t i = (size_t)blockIdx.x * 256 + threadIdx.x;
    if (i >= total) return;
    int b = i / ((size_t)K * N);
    size_t rem = i - (size_t)b * K * N;
    int k = rem / N, n = rem % N;
    dst[(size_t)b * K * N + (size_t)n * K + k] = f2b(src[i]);
}

// ---------------------------------------------------------------------------
// fp32 GEMM (input projections only), optional bf16 output copy
// ---------------------------------------------------------------------------
template <int K>
__launch_bounds__(256)
__global__ void gemm_k(const float* __restrict__ A, const float* __restrict__ W,
                       const float* __restrict__ bias, float* __restrict__ out,
                       unsigned short* __restrict__ outb, int N, int act) {
    constexpr int KC = (K <= 128) ? K : 128;
    __shared__ float As[32][KC + 1];
    __shared__ float Ws[KC * 64];
    const int tid = threadIdx.x;
    const size_t row0 = (size_t)blockIdx.x * 32;
    const int tx = tid & 15, ty = tid >> 4;
    const int c0 = tx * 4, r0 = ty * 2;

    for (int nc0 = 0; nc0 < N; nc0 += 64) {
        float acc[2][4] = {{0.f, 0.f, 0.f, 0.f}, {0.f, 0.f, 0.f, 0.f}};
        for (int kc0 = 0; kc0 < K; kc0 += KC) {
            __syncthreads();
            for (int idx = tid; idx < 32 * KC / 4; idx += 256) {
                int r = idx / (KC / 4);
                int kk = (idx % (KC / 4)) * 4;
                float4 v = *(const float4*)(A + (row0 + r) * K + kc0 + kk);
                As[r][kk] = v.x; As[r][kk + 1] = v.y;
                As[r][kk + 2] = v.z; As[r][kk + 3] = v.w;
            }
            for (int idx = tid; idx < KC * 16; idx += 256) {
                int k = idx >> 4;
                int cc = (idx & 15) * 4;
                *(float4*)&Ws[k * 64 + cc] =
                    *(const float4*)(W + (size_t)(kc0 + k) * N + nc0 + cc);
            }
            __syncthreads();
#pragma unroll 4
            for (int k = 0; k < KC; ++k) {
                float a0 = As[r0][k], a1 = As[r0 + 1][k];
                float4 w = *(const float4*)&Ws[k * 64 + c0];
                acc[0][0] += a0 * w.x; acc[0][1] += a0 * w.y;
                acc[0][2] += a0 * w.z; acc[0][3] += a0 * w.w;
                acc[1][0] += a1 * w.x; acc[1][1] += a1 * w.y;
                acc[1][2] += a1 * w.z; acc[1][3] += a1 * w.w;
            }
        }
#pragma unroll
        for (int i = 0; i < 2; ++i) {
            size_t off = (row0 + r0 + i) * N + nc0 + c0;
            float4 v = make_float4(acc[i][0], acc[i][1], acc[i][2], acc[i][3]);
            if (bias) {
                float4 b = *(const float4*)(bias + nc0 + c0);
                v.x += b.x; v.y += b.y; v.z += b.z; v.w += b.w;
            }
            if (act) {
                v.x = silu_f(v.x); v.y = silu_f(v.y);
                v.z = silu_f(v.z); v.w = silu_f(v.w);
            }
            if (out) *(float4*)(out + off) = v;
            if (outb) {
                ushort4 u = make_ushort4(f2b(v.x), f2b(v.y), f2b(v.z), f2b(v.w));
                *(ushort4*)(outb + off) = u;
            }
        }
    }
}

__global__ void combine_rbf(const float* __restrict__ W1, const float* __restrict__ W2,
                            float* __restrict__ C) {
    int l = blockIdx.x;
    const float* w1 = W1 + l * 48;
    const float* w2 = W2 + l * 1024;
    float* c = C + l * 768;
    for (int idx = threadIdx.x; idx < 768; idx += 256) {
        int j = idx >> 7, h = idx & 127;
        float s = 0.f;
#pragma unroll
        for (int p = 0; p < 8; ++p) s += w1[j * 8 + p] * w2[p * 128 + h];
        c[idx] = s;
    }
}

// ------------------------- CSR build -------------------------
__global__ void hist_kernel(const int* __restrict__ idx, int n, int* __restrict__ cnt) {
    int t = blockIdx.x * 256 + threadIdx.x;
    if (t < n) atomicAdd(&cnt[idx[t]], 1);
}

__launch_bounds__(1024)
__global__ void scan1(const int* __restrict__ cnt, int n, int* __restrict__ offs,
                      int* __restrict__ partials) {
    __shared__ int tmp[1024];
    int tid = threadIdx.x;
    int i = blockIdx.x * 1024 + tid;
    int v = (i < n) ? cnt[i] : 0;
    tmp[tid] = v; __syncthreads();
    for (int d = 1; d < 1024; d <<= 1) {
        int t = (tid >= d) ? tmp[tid - d] : 0; __syncthreads();
        tmp[tid] += t; __syncthreads();
    }
    if (i < n) offs[i] = tmp[tid] - v;
    if (tid == 1023) partials[blockIdx.x] = tmp[1023];
}

__launch_bounds__(1024)
__global__ void scan2(int* __restrict__ partials, int nb, int n, int* __restrict__ offs) {
    __shared__ int tmp[1024];
    int tid = threadIdx.x;
    int v = (tid < nb) ? partials[tid] : 0;
    tmp[tid] = v; __syncthreads();
    for (int d = 1; d < 1024; d <<= 1) {
        int t = (tid >= d) ? tmp[tid - d] : 0; __syncthreads();
        tmp[tid] += t; __syncthreads();
    }
    if (tid < nb) partials[tid] = tmp[tid] - v;
    if (tid == 1023) offs[n] = tmp[1023];
}

__launch_bounds__(1024)
__global__ void scan3(int n, int* __restrict__ offs, const int* __restrict__ partials,
                      int* __restrict__ cur) {
    int i = blockIdx.x * 1024 + threadIdx.x;
    if (i < n) { int o = offs[i] + partials[blockIdx.x]; offs[i] = o; cur[i] = o; }
}

__global__ void fill_kernel(const int* __restrict__ idx, int n,
                            int* __restrict__ cur, int* __restrict__ lst) {
    int t = blockIdx.x * 256 + threadIdx.x;
    if (t < n) {
        int p = atomicAdd(&cur[idx[t]], 1);
        lst[p] = t;
    }
}

// ------------------------ triplet stage ------------------------
__launch_bounds__(128)
__global__ void p8_kernel(const float* __restrict__ sbf, const float* __restrict__ W1,
                          float* __restrict__ p8) {
    __shared__ float S[128 * 43];
    __shared__ float Wl[SBF_DIM * 8];
    int tid = threadIdx.x;
    for (int i = tid; i < SBF_DIM * 8; i += 128) Wl[i] = W1[i];
    size_t base = (size_t)blockIdx.x * 128;
    int rows = (TT - base) < 128 ? (int)(TT - base) : 128;
    const float* src = sbf + base * SBF_DIM;
    for (int i = tid; i < rows * SBF_DIM; i += 128) {
        int r = i / SBF_DIM, j = i - r * SBF_DIM;
        S[r * 43 + j] = src[i];
    }
    __syncthreads();
    if (tid >= rows) return;
    float pv[8] = {0.f, 0.f, 0.f, 0.f, 0.f, 0.f, 0.f, 0.f};
    for (int j = 0; j < SBF_DIM; ++j) {
        float sv = S[tid * 43 + j];
#pragma unroll
        for (int p = 0; p < 8; ++p) pv[p] += sv * Wl[j * 8 + p];
    }
    float4* o = (float4*)(p8 + (base + tid) * 8);
    o[0] = make_float4(pv[0], pv[1], pv[2], pv[3]);
    o[1] = make_float4(pv[4], pv[5], pv[6], pv[7]);
}

__launch_bounds__(256)
__global__ void triplet_gather(const float* __restrict__ p8, const float* __restrict__ W2,
                               const unsigned short* __restrict__ xkj,
                               const int* __restrict__ idx_kj,
                               const int* __restrict__ offsT, const int* __restrict__ tlist,
                               unsigned short* __restrict__ agg) {
    int lane = threadIdx.x & 63;
    int wv = threadIdx.x >> 6;
    int e = blockIdx.x * 4 + wv;
    if (e >= EE) return;
    float w2c[8];
#pragma unroll
    for (int p = 0; p < 8; ++p) w2c[p] = W2[p * INTD + lane];
    int b = offsT[e], en = offsT[e + 1];
    float acc = 0.f;
    for (int q = b; q < en; ++q) {
        int t = tlist[q];
        int k = idx_kj[t];
        const float4* pr = (const float4*)(p8 + (size_t)t * 8);
        float4 p0 = pr[0], p1 = pr[1];
        float s = p0.x * w2c[0] + p0.y * w2c[1] + p0.z * w2c[2] + p0.w * w2c[3]
                + p1.x * w2c[4] + p1.y * w2c[5] + p1.z * w2c[6] + p1.w * w2c[7];
        acc += s * b2f(xkj[(size_t)k * INTD + lane]);
    }
    agg[(size_t)e * INTD + lane] = f2b(acc);
}

__launch_bounds__(256)
__global__ void e2_gather(const float* __restrict__ rbf, const float* __restrict__ Wr,
                          const float* __restrict__ e1f, const int* __restrict__ offsE,
                          const int* __restrict__ elist, float* __restrict__ vseg) {
    int h = threadIdx.x & 127;
    int sub = threadIdx.x >> 7;
    int n = blockIdx.x * 2 + sub;
    if (n >= NN) return;
    float c0 = Wr[0 * 128 + h], c1 = Wr[1 * 128 + h], c2 = Wr[2 * 128 + h],
          c3 = Wr[3 * 128 + h], c4 = Wr[4 * 128 + h], c5 = Wr[5 * 128 + h];
    int b = offsE[n], en = offsE[n + 1];
    float a0 = 0.f, a1 = 0.f, a2 = 0.f, a3 = 0.f;
    int q = b;
    for (; q + 4 <= en; q += 4) {
        int ea = elist[q], eb = elist[q + 1], ec = elist[q + 2], ed = elist[q + 3];
        const float* ra = rbf + (size_t)ea * NRAD;
        const float* rb = rbf + (size_t)eb * NRAD;
        const float* rc = rbf + (size_t)ec * NRAD;
        const float* rd = rbf + (size_t)ed * NRAD;
        float fa = e1f[(size_t)ea * 128 + h];
        float fb = e1f[(size_t)eb * 128 + h];
        float fc = e1f[(size_t)ec * 128 + h];
        float fd = e1f[(size_t)ed * 128 + h];
        float sa = ra[0] * c0 + ra[1] * c1 + ra[2] * c2 + ra[3] * c3 + ra[4] * c4 + ra[5] * c5;
        float sb = rb[0] * c0 + rb[1] * c1 + rb[2] * c2 + rb[3] * c3 + rb[4] * c4 + rb[5] * c5;
        float sc = rc[0] * c0 + rc[1] * c1 + rc[2] * c2 + rc[3] * c3 + rc[4] * c4 + rc[5] * c5;
        float sd = rd[0] * c0 + rd[1] * c1 + rd[2] * c2 + rd[3] * c3 + rd[4] * c4 + rd[5] * c5;
        a0 += sa * fa; a1 += sb * fb; a2 += sc * fc; a3 += sd * fd;
    }
    for (; q < en; ++q) {
        int e = elist[q];
        const float* rr = rbf + (size_t)e * NRAD;
        float s = rr[0] * c0 + rr[1] * c1 + rr[2] * c2 + rr[3] * c3 + rr[4] * c4 + rr[5] * c5;
        a0 += s * e1f[(size_t)e * 128 + h];
    }
    vseg[(size_t)n * 128 + h] = (a0 + a1) + (a2 + a3);
}

__global__ void scatter_u0(const float* __restrict__ v, const int* __restrict__ batch,
                           float* __restrict__ u0) {
    int idx = blockIdx.x * 256 + threadIdx.x;
    int h = idx & 127;
    int n = idx >> 7;
    atomicAdd(&u0[(size_t)batch[n] * 128 + h], v[idx]);
}

__global__ void final_out(const float* __restrict__ u0, const float* __restrict__ sb,
                          float* __restrict__ out) {
    int idx = blockIdx.x * 256 + threadIdx.x;
    out[idx] = u0[idx] + sb[idx >> 7];
}

extern "C" void kernel_launch(void* const* d_in, const int* in_sizes, int n_in,
                              void* d_out, int out_size, void* d_ws, size_t ws_size,
                              hipStream_t stream) {
    const float* x         = (const float*)d_in[0];
    const float* edge_attr = (const float*)d_in[1];
    const float* rbf       = (const float*)d_in[2];
    const float* sbf       = (const float*)d_in[3];
    const int*   iidx      = (const int*)d_in[4];
    const int*   idx_kj    = (const int*)d_in[5];
    const int*   idx_ji    = (const int*)d_in[6];
    const int*   batch     = (const int*)d_in[7];
    const float* W_node    = (const float*)d_in[8];
    const float* W_edge    = (const float*)d_in[9];
    const float* We_rbf1   = (const float*)d_in[10];
    const float* We_rbf2   = (const float*)d_in[11];
    const float* We_sbf1   = (const float*)d_in[12];
    const float* We_sbf2   = (const float*)d_in[13];
    const float* We_rbf    = (const float*)d_in[14];
    const float* We_kj     = (const float*)d_in[15];
    const float* be_kj     = (const float*)d_in[16];
    const float* We_ji     = (const float*)d_in[17];
    const float* be_ji     = (const float*)d_in[18];
    const float* We_down   = (const float*)d_in[19];
    const float* We_up     = (const float*)d_in[20];
    const float* We_cat    = (const float*)d_in[21];
    const float* Wres_b    = (const float*)d_in[22];
    const float* bres_b    = (const float*)d_in[23];
    const float* We_lin    = (const float*)d_in[24];
    const float* be_lin    = (const float*)d_in[25];
    const float* Wres_a    = (const float*)d_in[26];
    const float* bres_a    = (const float*)d_in[27];
    const float* Wv_up     = (const float*)d_in[28];
    const float* bv_up     = (const float*)d_in[29];
    const float* Wv_lins   = (const float*)d_in[30];
    const float* bv_lins   = (const float*)d_in[31];
    const float* Wv_out    = (const float*)d_in[32];
    float* out = (float*)d_out;

    // ---- workspace layout ----
    unsigned short* e1b  = (unsigned short*)d_ws;            // E*128 bf16
    unsigned short* buf1 = e1b  + (size_t)EE * HH;           // E*128 bf16 (x_ji)
    unsigned short* scr2 = buf1 + (size_t)EE * HH;           // E*128 slot (p8 alias + wtv)
    unsigned short* bufC = scr2 + (size_t)EE * HH;           // E*64 bf16 (xkj_down)
    unsigned short* bufD = bufC + (size_t)EE * INTD;         // E*64 bf16 (agg)
    unsigned short* endu = bufD + (size_t)EE * INTD;
    float* e1f    = (float*)endu;                            // E*128 fp32 master
    float* tail   = e1f + (size_t)EE * HH;
    float* u0     = tail;                                    // B*128
    float* sbatch = u0 + BB * HH;                            // 256
    float* Crbf   = sbatch + 256;                            // 4*768
    int*   iptr   = (int*)(Crbf + 4 * 768);
    int* cntT  = iptr;               iptr += EE;
    int* offsT = iptr;               iptr += EE + 1;
    int* curT  = iptr;               iptr += EE;
    int* tlist = iptr;               iptr += TT;
    int* cntE  = iptr;               iptr += NN;
    int* offsE = iptr;               iptr += NN + 1;
    int* curE  = iptr;               iptr += NN;
    int* elist = iptr;               iptr += EE;
    int* partials = iptr;            iptr += 1024;
    unsigned short* wptr = (unsigned short*)iptr;
    unsigned short* wt_ji   = wptr;  wptr += 4 * 16384;
    unsigned short* wt_kj   = wptr;  wptr += 4 * 16384;
    unsigned short* wt_down = wptr;  wptr += 4 * 8192;
    unsigned short* wt_up   = wptr;  wptr += 4 * 8192;
    unsigned short* wt_cat  = wptr;  wptr += 4 * 16384;
    unsigned short* wt_resb = wptr;  wptr += 8 * 16384;
    unsigned short* wt_lin  = wptr;  wptr += 4 * 16384;
    unsigned short* wt_resa = wptr;  wptr += 16 * 16384;
    float* p8 = (float*)scr2;                                // [T,8] fp32 (first 48MB of scr2)
    // node-pipeline weights live in scr2 past the p8 region (proven-allocated slack)
    unsigned short* wtv_up  = scr2 + (size_t)TT * 16;        // 4*[256][128] bf16
    unsigned short* wtv_lin = wtv_up + 4 * 32768;            // 12*[256][256] bf16
    float* vseg = (float*)bufC;                              // N*128 fp32 (post-MK2)

    hipMemsetAsync(u0, 0, (size_t)BB * HH * sizeof(float), stream);
    hipMemsetAsync(sbatch, 0, 256 * sizeof(float), stream);
    combine_rbf<<<4, 256, 0, stream>>>(We_rbf1, We_rbf2, Crbf);

    transpose_w<<<(4 * 16384 + 255) / 256, 256, 0, stream>>>(We_ji, wt_ji, 4, 128, 128);
    transpose_w<<<(4 * 16384 + 255) / 256, 256, 0, stream>>>(We_kj, wt_kj, 4, 128, 128);
    transpose_w<<<(4 * 8192 + 255) / 256, 256, 0, stream>>>(We_down, wt_down, 4, 128, 64);
    transpose_w<<<(4 * 8192 + 255) / 256, 256, 0, stream>>>(We_up, wt_up, 4, 64, 128);
    transpose_w<<<(4 * 16384 + 255) / 256, 256, 0, stream>>>(We_cat, wt_cat, 4, 128, 128);
    transpose_w<<<(8 * 16384 + 255) / 256, 256, 0, stream>>>(Wres_b, wt_resb, 8, 128, 128);
    transpose_w<<<(4 * 16384 + 255) / 256, 256, 0, stream>>>(We_lin, wt_lin, 4, 128, 128);
    transpose_w<<<(16 * 16384 + 255) / 256, 256, 0, stream>>>(Wres_a, wt_resa, 16, 128, 128);
    transpose_w<<<(4 * 128 * 256 + 255) / 256, 256, 0, stream>>>(Wv_up, wtv_up, 4, 128, 256);
    transpose_w<<<(12 * 256 * 256 + 255) / 256, 256, 0, stream>>>(Wv_lins, wtv_lin, 12, 256, 256);

    hipMemsetAsync(cntT, 0, EE * sizeof(int), stream);
    hipMemsetAsync(cntE, 0, NN * sizeof(int), stream);
    hist_kernel<<<(TT + 255) / 256, 256, 0, stream>>>(idx_ji, TT, cntT);
    hist_kernel<<<(EE + 255) / 256, 256, 0, stream>>>(iidx, EE, cntE);
    int nbT = (EE + 1023) / 1024, nbE = (NN + 1023) / 1024;
    scan1<<<nbT, 1024, 0, stream>>>(cntT, EE, offsT, partials);
    scan2<<<1, 1024, 0, stream>>>(partials, nbT, EE, offsT);
    scan3<<<nbT, 1024, 0, stream>>>(EE, offsT, partials, curT);
    fill_kernel<<<(TT + 255) / 256, 256, 0, stream>>>(idx_ji, TT, curT, tlist);
    scan1<<<nbE, 1024, 0, stream>>>(cntE, NN, offsE, partials);
    scan2<<<1, 1024, 0, stream>>>(partials, nbE, NN, offsE);
    scan3<<<nbE, 1024, 0, stream>>>(NN, offsE, partials, curE);
    fill_kernel<<<(EE + 255) / 256, 256, 0, stream>>>(iidx, EE, curE, elist);

    gemm_k<12><<<EE / 32, 256, 0, stream>>>(edge_attr, W_edge, nullptr, e1f, e1b, HH, 0);
    gemm_k<48><<<NN / 32, 256, 0, stream>>>(x, W_node, nullptr, vseg, nullptr, HH, 0);
    scatter_u0<<<NN * HH / 256, 256, 0, stream>>>(vseg, batch, u0);

    const int GR = EE / 128;            // 3125
    const int GV = (NN + 127) / 128;    // 157
    for (int l = 0; l < 4; ++l) {
        mk1<<<GR, 512, 0, stream>>>(e1b, wt_ji + l * 16384, wt_kj + l * 16384,
                                    wt_down + l * 8192, be_ji + l * HH, be_kj + l * HH,
                                    rbf, Crbf + l * 768, buf1, bufC);
        p8_kernel<<<(TT + 127) / 128, 128, 0, stream>>>(sbf, We_sbf1 + l * SBF_DIM * 8, p8);
        triplet_gather<<<EE / 4, 256, 0, stream>>>(p8, We_sbf2 + l * 8 * INTD, bufC,
                                                   idx_kj, offsT, tlist, bufD);
        mk2<<<GR, 512, 0, stream>>>(bufD, buf1, e1f, e1b,
            wt_up + l * 8192, wt_cat + l * 16384,
            wt_resb + (l * 2 + 0) * 16384, wt_resb + (l * 2 + 1) * 16384,
            wt_lin + l * 16384,
            wt_resa + ((l * 2 + 0) * 2 + 0) * 16384, wt_resa + ((l * 2 + 0) * 2 + 1) * 16384,
            wt_resa + ((l * 2 + 1) * 2 + 0) * 16384, wt_resa + ((l * 2 + 1) * 2 + 1) * 16384,
            bres_b + (l * 2 + 0) * HH, bres_b + (l * 2 + 1) * HH, be_lin + l * HH,
            bres_a + ((l * 2 + 0) * 2 + 0) * HH, bres_a + ((l * 2 + 0) * 2 + 1) * HH,
            bres_a + ((l * 2 + 1) * 2 + 0) * HH, bres_a + ((l * 2 + 1) * 2 + 1) * HH);
        e2_gather<<<(NN + 1) / 2, 256, 0, stream>>>(rbf, We_rbf + (size_t)l * NRAD * HH,
                                                    e1f, offsE, elist, vseg);
        mkv<<<GV, 512, 0, stream>>>(vseg, wtv_up + (size_t)l * 32768,
                                    wtv_lin + (size_t)l * 3 * 65536,
                                    bv_up + l * OUT_EMB, bv_lins + (size_t)l * 3 * OUT_EMB,
                                    Wv_out + l * OUT_EMB, batch, sbatch);
    }
    final_out<<<BB * HH / 256, 256, 0, stream>>>(u0, sbatch, out);
}